// Round 5
// baseline (608.452 us; speedup 1.0000x reference)
//
#include <hip/hip_runtime.h>

// ---- problem constants --------------------------------------------------
static constexpr int OMODE = 2, PMODE = 4, NZ = 8;
static constexpr int NYX = 512;   // object plane 512x512
static constexpr int NP  = 128;   // probe / tile 128x128
static constexpr int BATCH = 64;
static constexpr int LSTR = 129;  // padded LDS line stride (float2 units)
static constexpr float INV_N2 = 1.0f / 16384.0f;   // 1/(128*128) ifft2 norm

__device__ __forceinline__ int br7(int x) { return (int)(__brev((unsigned)x) >> 25); }

// ---- cross-lane exchange: DPP / permlane / swizzle ----------------------
template<int CTRL>
__device__ __forceinline__ float dppf(float x) {
  int i = __float_as_int(x);
  int r = __builtin_amdgcn_update_dpp(i, i, CTRL, 0xF, 0xF, false);
  return __int_as_float(r);
}

// partner value at lane^H for all 64 lanes (validated in R4)
template<int H>
__device__ __forceinline__ float shx(float x, int lane) {
  if constexpr (H == 1) {
    return dppf<0xB1>(x);                       // quad_perm [1,0,3,2]
  } else if constexpr (H == 2) {
    return dppf<0x4E>(x);                       // quad_perm [2,3,0,1]
  } else if constexpr (H == 4) {
    return __int_as_float(__builtin_amdgcn_ds_swizzle(__float_as_int(x), 0x101F));
  } else if constexpr (H == 8) {
    return dppf<0x128>(x);                      // row_ror:8 == xor 8 within row16
  } else if constexpr (H == 16) {
#if __has_builtin(__builtin_amdgcn_permlane16_swap)
    unsigned u = __float_as_uint(x);
    auto r = __builtin_amdgcn_permlane16_swap(u, u, false, false);
    return __uint_as_float(((lane >> 4) & 1) ? r[0] : r[1]);
#else
    return __shfl_xor(x, 16);
#endif
  } else {  // H == 32
#if __has_builtin(__builtin_amdgcn_permlane32_swap)
    unsigned u = __float_as_uint(x);
    auto r = __builtin_amdgcn_permlane32_swap(u, u, false, false);
    return __uint_as_float((lane >> 5) ? r[0] : r[1]);
#else
    return __shfl_xor(x, 32);
#endif
  }
}

// Per-thread twiddles, compile-time indexed only -> 20 VGPRs.
struct Tw {
  float tc6, ts6;            // cos/sin(pi*lane/64) for the register stage
  float g[6];                // +1 lower lane of pair, -1 upper
  float dwr[6], dwi[6];      // DIF post-mul: up ? conj(w) : 1   (DIT uses dwr,-dwi)
};

__device__ __forceinline__ void cmul(float2& a, float br_, float bi_) {
  float x = a.x * br_ - a.y * bi_;
  a.y = a.x * bi_ + a.y * br_;
  a.x = x;
}
__device__ __forceinline__ float2 cmul2(float2 a, float2 b) {
  return make_float2(a.x * b.x - a.y * b.y, a.x * b.y + a.y * b.x);
}

template<int S>
__device__ __forceinline__ void dif_stage(float2& A, float2& B, const Tw& tw, int lane) {
  constexpr int H = 1 << S;
  float tx, ty, dx, dy;
  tx = shx<H>(A.x, lane); ty = shx<H>(A.y, lane);
  dx = tx + tw.g[S] * A.x; dy = ty + tw.g[S] * A.y;
  A.x = dx * tw.dwr[S] - dy * tw.dwi[S];
  A.y = dx * tw.dwi[S] + dy * tw.dwr[S];
  tx = shx<H>(B.x, lane); ty = shx<H>(B.y, lane);
  dx = tx + tw.g[S] * B.x; dy = ty + tw.g[S] * B.y;
  B.x = dx * tw.dwr[S] - dy * tw.dwi[S];
  B.y = dx * tw.dwi[S] + dy * tw.dwr[S];
}

template<int S>
__device__ __forceinline__ void dit_stage(float2& A, float2& B, const Tw& tw, int lane) {
  constexpr int H = 1 << S;
  float mx, my, tx, ty;
  mx =  A.x * tw.dwr[S] + A.y * tw.dwi[S];
  my = -A.x * tw.dwi[S] + A.y * tw.dwr[S];
  tx = shx<H>(mx, lane); ty = shx<H>(my, lane);
  A.x = tx + tw.g[S] * mx; A.y = ty + tw.g[S] * my;
  mx =  B.x * tw.dwr[S] + B.y * tw.dwi[S];
  my = -B.x * tw.dwi[S] + B.y * tw.dwr[S];
  tx = shx<H>(mx, lane); ty = shx<H>(my, lane);
  B.x = tx + tw.g[S] * mx; B.y = ty + tw.g[S] * my;
}

// Forward 128-pt DIF: natural-order input -> bit-reversed-order slots.
__device__ __forceinline__ void dif128(float2& A, float2& B, const Tw& tw, int lane) {
  { // register stage h=64: w = e^{-i*pi*lane/64}
    float dr = A.x - B.x, di = A.y - B.y;
    A.x += B.x; A.y += B.y;
    B.x = dr * tw.tc6 + di * tw.ts6;
    B.y = di * tw.tc6 - dr * tw.ts6;
  }
  dif_stage<5>(A, B, tw, lane);
  dif_stage<4>(A, B, tw, lane);
  dif_stage<3>(A, B, tw, lane);
  dif_stage<2>(A, B, tw, lane);
  dif_stage<1>(A, B, tw, lane);
  dif_stage<0>(A, B, tw, lane);
}

// Inverse (unnormalized) 128-pt DIT: bit-reversed slots -> natural order.
__device__ __forceinline__ void dit128(float2& A, float2& B, const Tw& tw, int lane) {
  dit_stage<0>(A, B, tw, lane);
  dit_stage<1>(A, B, tw, lane);
  dit_stage<2>(A, B, tw, lane);
  dit_stage<3>(A, B, tw, lane);
  dit_stage<4>(A, B, tw, lane);
  dit_stage<5>(A, B, tw, lane);
  { // register stage h=64: w = e^{+i*pi*lane/64}
    float mx = B.x * tw.tc6 - B.y * tw.ts6;
    float my = B.x * tw.ts6 + B.y * tw.tc6;
    B.x = A.x - mx; B.y = A.y - my;
    A.x += mx; A.y += my;
  }
}

// Pre-scramble H into workspace: hp[px][py] = H[br(py)][br(px)] * (1/N^2).
__global__ void __launch_bounds__(256) init_hpre(const float* __restrict__ H,
                                                 float2* __restrict__ hp) {
  int i = blockIdx.x * blockDim.x + threadIdx.x;
  if (i >= NP * NP) return;
  int px = i >> 7, py = i & (NP - 1);
  int ky = br7(py), kx = br7(px);
  hp[px * NP + py] = make_float2(H[(ky * NP + kx) * 2 + 0] * INV_N2,
                                 H[(ky * NP + kx) * 2 + 1] * INV_N2);
}

// Per-n shift ramps at bit-reversed slot positions.
// rampy[n][slot] = e^{-2pi i fy(br7(slot)) sh0} * INV_N2 ; rampx[n][slot] = e^{-2pi i fx(br7(slot)) sh1}
__global__ void __launch_bounds__(256) init_ramp(const float* __restrict__ shifts,
                                                 const int* __restrict__ indices,
                                                 float2* __restrict__ rampy,
                                                 float2* __restrict__ rampx) {
  int i = blockIdx.x * blockDim.x + threadIdx.x;
  if (i >= 2 * BATCH * NP) return;
  int which = (i >= BATCH * NP) ? 1 : 0;
  int r = i - which * BATCH * NP;
  int n = r >> 7, slot = r & (NP - 1);
  int pos = indices[n];
  float sh = shifts[2 * pos + which];
  int k = br7(slot);
  float f = (float)(k < 64 ? k : k - 128) * (1.f / 128.f);
  float s, c;
  __sincosf(-6.28318530717959f * f * sh, &s, &c);
  if (!which) rampy[n * NP + slot] = make_float2(c * INV_N2, s * INV_N2);
  else        rampx[n * NP + slot] = make_float2(c, s);
}

// Sum the 8 (o,p) partials per batch element. part tile is TRANSPOSED: [blk][kx][ky].
__global__ void __launch_bounds__(256) reduce_dp(const float* __restrict__ part,
                                                 float* __restrict__ dp) {
  int i = blockIdx.x * 256 + threadIdx.x;
  if (i >= BATCH * NP * NP) return;
  int n = i >> 14;
  int r = i & (NP * NP - 1);
  int ky = r >> 7, kx = r & (NP - 1);
  const float* b = part + ((size_t)n * 8 << 14) + (kx << 7) + ky;
  float s = 0.f;
#pragma unroll
  for (int j = 0; j < 8; ++j) s += b[(size_t)j << 14];
  dp[i] = s;
}

__global__ void __launch_bounds__(1024) ptycho_chain(
    const float* __restrict__ obja, const float* __restrict__ objp,
    const float* __restrict__ probe, const float* __restrict__ shifts,
    const float* __restrict__ H, const float2* __restrict__ hpre,
    const float2* __restrict__ rampy, const float2* __restrict__ rampx,
    const float* __restrict__ occu, const int* __restrict__ indices,
    const int* __restrict__ crop, float* __restrict__ dp,
    float* __restrict__ part, int mode_ws)
{
  extern __shared__ float2 fld[];          // [128][LSTR] interleaved re/im

  const int blk  = blockIdx.x;             // n*8 + o*4 + p
  const int n    = blk >> 3;
  const int o    = (blk >> 2) & 1;
  const int p    = blk & 3;
  const int tid  = threadIdx.x;
  const int wid  = tid >> 6;               // 16 waves
  const int lane = tid & 63;

  const int   pos = indices[n];
  const int   cy  = crop[2 * pos + 0];
  const int   cx  = crop[2 * pos + 1];
  const float wocc = occu[o];

  // ---- twiddles (20 VGPRs) ----------------------------------------------
  Tw tw;
#pragma unroll
  for (int s = 0; s < 6; ++s) {
    int h = 1 << s;
    int j = lane & (h - 1);
    float ang = 3.14159265358979f * (float)j / (float)h;
    float ts_, tc_;
    __sincosf(ang, &ts_, &tc_);
    bool up = (lane >> s) & 1;
    tw.g[s]   = up ? -1.f : 1.f;
    tw.dwr[s] = up ? tc_ : 1.f;
    tw.dwi[s] = up ? -ts_ : 0.f;
  }
  __sincosf(3.14159265358979f * (float)lane * (1.f / 64.f), &tw.ts6, &tw.tc6);

  // ---- P0: load probe rows + forward row FFT ----------------------------
  const float2* probe2 = (const float2*)probe;
#pragma unroll 1
  for (int k0 = 0; k0 < 8; k0 += 2) {
    int r0 = wid * 8 + k0;
    float2 A0 = probe2[(p * NP + r0) * NP + lane];
    float2 B0 = probe2[(p * NP + r0) * NP + lane + 64];
    float2 A1 = probe2[(p * NP + r0 + 1) * NP + lane];
    float2 B1 = probe2[(p * NP + r0 + 1) * NP + lane + 64];
    dif128(A0, B0, tw, lane); dif128(A1, B1, tw, lane);
    fld[r0 * LSTR + lane]            = A0; fld[r0 * LSTR + lane + 64]       = B0;
    fld[(r0 + 1) * LSTR + lane]      = A1; fld[(r0 + 1) * LSTR + lane + 64] = B1;
  }
  __syncthreads();

  // fallback-only ramp multiply (no workspace): inline sincos
  auto ramp_mul_fb = [&](float2& A, float2& B, int c) {
    float sh0v = shifts[2 * pos], sh1v = shifts[2 * pos + 1];
    int kxc = br7(c);
    float fx = (float)(kxc < 64 ? kxc : kxc - 128) * (1.f / 128.f);
    int ky0 = br7(lane);
    float fy0 = (float)(ky0 < 64 ? ky0 : ky0 - 128) * (1.f / 128.f);
    int ky1 = ky0 + 1;
    float fy1 = (float)(ky1 < 64 ? ky1 : ky1 - 128) * (1.f / 128.f);
    float com = fx * sh1v;
    float s0, c0_, s1, c1_;
    __sincosf(-6.28318530717959f * (fy0 * sh0v + com), &s0, &c0_);
    __sincosf(-6.28318530717959f * (fy1 * sh0v + com), &s1, &c1_);
    cmul(A, c0_ * INV_N2, s0 * INV_N2);
    cmul(B, c1_ * INV_N2, s1 * INV_N2);
  };
  auto h_mul_fb = [&](float2& A, float2& B, int c) {
    int kx = br7(c), ky0 = br7(lane);
    float hr0 = H[(ky0 * NP + kx) * 2], hi0 = H[(ky0 * NP + kx) * 2 + 1];
    float hr1 = H[((ky0 + 1) * NP + kx) * 2], hi1 = H[((ky0 + 1) * NP + kx) * 2 + 1];
    cmul(A, hr0 * INV_N2, hi0 * INV_N2);
    cmul(B, hr1 * INV_N2, hi1 * INV_N2);
  };

  // ---- column phase: Fcol, freq multiply, invCol ------------------------
  auto cphase = [&](int mode) {
    float2 ry0, ry1;
    if (mode == 0 && mode_ws) {
      ry0 = rampy[n * NP + lane];
      ry1 = rampy[n * NP + lane + 64];
    }
#pragma unroll 1
    for (int k0 = 0; k0 < 8; k0 += 2) {
      int c0 = wid * 8 + k0, c1 = c0 + 1;
      float2 h00, h01, h10, h11;
      if (mode == 1 && mode_ws) {
        h00 = hpre[c0 * NP + lane]; h01 = hpre[c0 * NP + lane + 64];
        h10 = hpre[c1 * NP + lane]; h11 = hpre[c1 * NP + lane + 64];
      }
      float2 rx0, rx1;
      if (mode == 0 && mode_ws) {
        rx0 = rampx[n * NP + c0]; rx1 = rampx[n * NP + c1];
      }
      float2 A0 = fld[lane * LSTR + c0], B0 = fld[(lane + 64) * LSTR + c0];
      float2 A1 = fld[lane * LSTR + c1], B1 = fld[(lane + 64) * LSTR + c1];
      dif128(A0, B0, tw, lane); dif128(A1, B1, tw, lane);
      if (mode == 0) {
        if (mode_ws) {
          float2 m; 
          m = cmul2(rx0, ry0); cmul(A0, m.x, m.y);
          m = cmul2(rx0, ry1); cmul(B0, m.x, m.y);
          m = cmul2(rx1, ry0); cmul(A1, m.x, m.y);
          m = cmul2(rx1, ry1); cmul(B1, m.x, m.y);
        } else {
          ramp_mul_fb(A0, B0, c0);
          ramp_mul_fb(A1, B1, c1);
        }
      } else {
        if (mode_ws) {
          cmul(A0, h00.x, h00.y); cmul(B0, h01.x, h01.y);
          cmul(A1, h10.x, h10.y); cmul(B1, h11.x, h11.y);
        } else {
          h_mul_fb(A0, B0, c0);
          h_mul_fb(A1, B1, c1);
        }
      }
      dit128(A0, B0, tw, lane); dit128(A1, B1, tw, lane);
      fld[lane * LSTR + c0]        = A0; fld[(lane + 64) * LSTR + c0] = B0;
      fld[lane * LSTR + c1]        = A1; fld[(lane + 64) * LSTR + c1] = B1;
    }
    __syncthreads();
  };

  // ---- row phase: invRow, multiply T(z), Frow ---------------------------
  auto rphase = [&](int z) {
#pragma unroll 1
    for (int k0 = 0; k0 < 8; k0 += 2) {
      int r0 = wid * 8 + k0;
      size_t ob0 = ((size_t)(o * NZ + z) * NYX + (size_t)(cy + r0)) * NYX + cx;
      size_t ob1 = ob0 + NYX;
      float pa00 = obja[ob0 + lane],      ph00 = objp[ob0 + lane];
      float pa01 = obja[ob0 + lane + 64], ph01 = objp[ob0 + lane + 64];
      float pa10 = obja[ob1 + lane],      ph10 = objp[ob1 + lane];
      float pa11 = obja[ob1 + lane + 64], ph11 = objp[ob1 + lane + 64];
      float2 A0 = fld[r0 * LSTR + lane],       B0 = fld[r0 * LSTR + lane + 64];
      float2 A1 = fld[(r0 + 1) * LSTR + lane], B1 = fld[(r0 + 1) * LSTR + lane + 64];
      dit128(A0, B0, tw, lane); dit128(A1, B1, tw, lane);
      float s, c;
      __sincosf(ph00, &s, &c); cmul(A0, pa00 * c, pa00 * s);
      __sincosf(ph01, &s, &c); cmul(B0, pa01 * c, pa01 * s);
      __sincosf(ph10, &s, &c); cmul(A1, pa10 * c, pa10 * s);
      __sincosf(ph11, &s, &c); cmul(B1, pa11 * c, pa11 * s);
      dif128(A0, B0, tw, lane); dif128(A1, B1, tw, lane);
      fld[r0 * LSTR + lane]            = A0; fld[r0 * LSTR + lane + 64]       = B0;
      fld[(r0 + 1) * LSTR + lane]      = A1; fld[(r0 + 1) * LSTR + lane + 64] = B1;
    }
    __syncthreads();
  };

  cphase(0);        // Fcol + ramp + invCol  (completes probe shift)
  rphase(0);        // invRow + T0 + Frow
#pragma unroll 1
  for (int z = 1; z < NZ; ++z) {
    cphase(1);      // Fcol + H + invCol     (propagation z-1 -> z)
    rphase(z);      // invRow + Tz + Frow
  }

  // ---- final column FFT -> |.|^2 -> store (transposed part tile) --------
#pragma unroll 1
  for (int k0 = 0; k0 < 8; k0 += 2) {
    int c0 = wid * 8 + k0, c1 = c0 + 1;
    float2 A0 = fld[lane * LSTR + c0], B0 = fld[(lane + 64) * LSTR + c0];
    float2 A1 = fld[lane * LSTR + c1], B1 = fld[(lane + 64) * LSTR + c1];
    dif128(A0, B0, tw, lane); dif128(A1, B1, tw, lane);
    int ky0 = br7(lane);
    float m00 = (A0.x * A0.x + A0.y * A0.y) * wocc;
    float m01 = (B0.x * B0.x + B0.y * B0.y) * wocc;
    float m10 = (A1.x * A1.x + A1.y * A1.y) * wocc;
    float m11 = (B1.x * B1.x + B1.y * B1.y) * wocc;
    if (mode_ws) {
      size_t b0 = ((size_t)blk << 14) + (size_t)br7(c0) * NP;
      size_t b1 = ((size_t)blk << 14) + (size_t)br7(c1) * NP;
      part[b0 + ky0]     = m00;
      part[b0 + ky0 + 1] = m01;
      part[b1 + ky0]     = m10;
      part[b1 + ky0 + 1] = m11;
    } else {
      size_t base = ((size_t)n << 14);
      atomicAdd(&dp[base + (size_t)ky0 * NP + br7(c0)],       m00);
      atomicAdd(&dp[base + (size_t)(ky0 + 1) * NP + br7(c0)], m01);
      atomicAdd(&dp[base + (size_t)ky0 * NP + br7(c1)],       m10);
      atomicAdd(&dp[base + (size_t)(ky0 + 1) * NP + br7(c1)], m11);
    }
  }
}

extern "C" void kernel_launch(void* const* d_in, const int* in_sizes, int n_in,
                              void* d_out, int out_size, void* d_ws, size_t ws_size,
                              hipStream_t stream) {
  const float* obja   = (const float*)d_in[0];
  const float* objp   = (const float*)d_in[1];
  const float* probe  = (const float*)d_in[2];
  const float* shifts = (const float*)d_in[3];
  const float* H      = (const float*)d_in[4];
  const float* occu   = (const float*)d_in[5];
  const int*   indices = (const int*)d_in[6];
  const int*   crop    = (const int*)d_in[7];
  float* dp = (float*)d_out;

  const size_t part_bytes  = (size_t)BATCH * OMODE * PMODE * NP * NP * sizeof(float); // 32 MB
  const size_t hpre_bytes  = (size_t)NP * NP * sizeof(float2);                        // 128 KB
  const size_t ramp_bytes  = (size_t)BATCH * NP * sizeof(float2);                     // 64 KB each
  const size_t need = part_bytes + hpre_bytes + 2 * ramp_bytes;

  int mode_ws = (ws_size >= need) ? 1 : 0;
  float*  part  = (float*)d_ws;
  float2* hpre  = (float2*)((char*)d_ws + part_bytes);
  float2* rampy = (float2*)((char*)d_ws + part_bytes + hpre_bytes);
  float2* rampx = (float2*)((char*)d_ws + part_bytes + hpre_bytes + ramp_bytes);

  if (mode_ws) {
    hipLaunchKernelGGL(init_hpre, dim3((NP * NP + 255) / 256), dim3(256), 0,
                       stream, H, hpre);
    hipLaunchKernelGGL(init_ramp, dim3((2 * BATCH * NP + 255) / 256), dim3(256), 0,
                       stream, shifts, indices, rampy, rampx);
  } else {
    // atomic fallback accumulates -> must zero output every call
    hipMemsetAsync(d_out, 0, (size_t)out_size * sizeof(float), stream);
  }

  const int lds_bytes = NP * LSTR * (int)sizeof(float2);  // 132096
  hipFuncSetAttribute((const void*)ptycho_chain,
                      hipFuncAttributeMaxDynamicSharedMemorySize, lds_bytes);
  hipLaunchKernelGGL(ptycho_chain, dim3(BATCH * OMODE * PMODE), dim3(1024),
                     lds_bytes, stream,
                     obja, objp, probe, shifts, H, hpre, rampy, rampx,
                     occu, indices, crop, dp, part, mode_ws);
  if (mode_ws) {
    hipLaunchKernelGGL(reduce_dp, dim3((BATCH * NP * NP + 255) / 256), dim3(256),
                       0, stream, part, dp);
  }
}

// Round 6
// 503.412 us; speedup vs baseline: 1.2087x; 1.2087x over previous
//
#include <hip/hip_runtime.h>

// ---- problem constants --------------------------------------------------
static constexpr int OMODE = 2, PMODE = 4, NZ = 8;
static constexpr int NYX = 512;   // object plane 512x512
static constexpr int NP  = 128;   // probe / tile 128x128
static constexpr int BATCH = 64;
static constexpr int LSTR = 129;  // padded LDS line stride (float2 units)
static constexpr float INV_N2 = 1.0f / 16384.0f;   // 1/(128*128) ifft2 norm

typedef float v2f __attribute__((ext_vector_type(2)));

__device__ __forceinline__ int br7(int x) { return (int)(__brev((unsigned)x) >> 25); }

__device__ __forceinline__ v2f splat2(float s) { return (v2f){s, s}; }
__device__ __forceinline__ v2f swapv(v2f v) { return __builtin_shufflevector(v, v, 1, 0); }
// a *= (br + i*bi)
__device__ __forceinline__ v2f cmulv(v2f a, float br_, float bi_) {
  return a * splat2(br_) + swapv(a) * (v2f){-bi_, bi_};
}
__device__ __forceinline__ v2f cmulvv(v2f a, v2f b) {
  return a * splat2(b.x) + swapv(a) * (v2f){-b.y, b.y};
}

// ---- cross-lane exchange: DPP / permlane / swizzle (validated R4/R5) ----
template<int CTRL>
__device__ __forceinline__ float dppf(float x) {
  int i = __float_as_int(x);
  int r = __builtin_amdgcn_update_dpp(i, i, CTRL, 0xF, 0xF, false);
  return __int_as_float(r);
}

template<int H>
__device__ __forceinline__ float shx(float x, int lane) {
  if constexpr (H == 1) {
    return dppf<0xB1>(x);                       // quad_perm [1,0,3,2]
  } else if constexpr (H == 2) {
    return dppf<0x4E>(x);                       // quad_perm [2,3,0,1]
  } else if constexpr (H == 4) {
    return __int_as_float(__builtin_amdgcn_ds_swizzle(__float_as_int(x), 0x101F));
  } else if constexpr (H == 8) {
    return dppf<0x128>(x);                      // row_ror:8 == xor 8 within row16
  } else if constexpr (H == 16) {
#if __has_builtin(__builtin_amdgcn_permlane16_swap)
    unsigned u = __float_as_uint(x);
    auto r = __builtin_amdgcn_permlane16_swap(u, u, false, false);
    return __uint_as_float(((lane >> 4) & 1) ? r[0] : r[1]);
#else
    return __shfl_xor(x, 16);
#endif
  } else {  // H == 32
#if __has_builtin(__builtin_amdgcn_permlane32_swap)
    unsigned u = __float_as_uint(x);
    auto r = __builtin_amdgcn_permlane32_swap(u, u, false, false);
    return __uint_as_float((lane >> 5) ? r[0] : r[1]);
#else
    return __shfl_xor(x, 32);
#endif
  }
}

template<int H>
__device__ __forceinline__ v2f shx2(v2f v, int lane) {
  return (v2f){shx<H>(v.x, lane), shx<H>(v.y, lane)};
}

// Per-thread twiddles, scalars only (compile-time indexed) -> 20 VGPRs.
struct Tw {
  float tc6, ts6;            // cos/sin(pi*lane/64) for the register stage
  float g[6];                // +1 lower lane of pair, -1 upper
  float dwr[6], dwi[6];      // DIF post-mul: up ? conj(w) : 1   (DIT uses dwr,-dwi)
};

template<int S>
__device__ __forceinline__ void dif_stage(v2f& A, v2f& B, const Tw& tw, int lane) {
  constexpr int H = 1 << S;
  v2f g2 = splat2(tw.g[S]);
  v2f wr = splat2(tw.dwr[S]);
  v2f win = (v2f){-tw.dwi[S], tw.dwi[S]};
  v2f d;
  d = shx2<H>(A, lane) + g2 * A;
  A = d * wr + swapv(d) * win;
  d = shx2<H>(B, lane) + g2 * B;
  B = d * wr + swapv(d) * win;
}

template<int S>
__device__ __forceinline__ void dit_stage(v2f& A, v2f& B, const Tw& tw, int lane) {
  constexpr int H = 1 << S;
  v2f g2 = splat2(tw.g[S]);
  v2f wr = splat2(tw.dwr[S]);
  v2f wip = (v2f){tw.dwi[S], -tw.dwi[S]};
  v2f m;
  m = A * wr + swapv(A) * wip;
  A = shx2<H>(m, lane) + g2 * m;
  m = B * wr + swapv(B) * wip;
  B = shx2<H>(m, lane) + g2 * m;
}

// Forward 128-pt DIF: natural-order input -> bit-reversed-order slots.
__device__ __forceinline__ void dif128(v2f& A, v2f& B, const Tw& tw, int lane) {
  { // register stage h=64: w = e^{-i*pi*lane/64}
    v2f d = A - B;
    A = A + B;
    B = d * splat2(tw.tc6) + swapv(d) * (v2f){tw.ts6, -tw.ts6};
  }
  dif_stage<5>(A, B, tw, lane);
  dif_stage<4>(A, B, tw, lane);
  dif_stage<3>(A, B, tw, lane);
  dif_stage<2>(A, B, tw, lane);
  dif_stage<1>(A, B, tw, lane);
  dif_stage<0>(A, B, tw, lane);
}

// Inverse (unnormalized) 128-pt DIT: bit-reversed slots -> natural order.
__device__ __forceinline__ void dit128(v2f& A, v2f& B, const Tw& tw, int lane) {
  dit_stage<0>(A, B, tw, lane);
  dit_stage<1>(A, B, tw, lane);
  dit_stage<2>(A, B, tw, lane);
  dit_stage<3>(A, B, tw, lane);
  dit_stage<4>(A, B, tw, lane);
  dit_stage<5>(A, B, tw, lane);
  { // register stage h=64: w = e^{+i*pi*lane/64}
    v2f m = B * splat2(tw.tc6) + swapv(B) * (v2f){-tw.ts6, tw.ts6};
    B = A - m;
    A = A + m;
  }
}

// Pre-scramble H into workspace: hp[px][py] = H[br(py)][br(px)] * (1/N^2).
__global__ void __launch_bounds__(256) init_hpre(const float* __restrict__ H,
                                                 float2* __restrict__ hp) {
  int i = blockIdx.x * blockDim.x + threadIdx.x;
  if (i >= NP * NP) return;
  int px = i >> 7, py = i & (NP - 1);
  int ky = br7(py), kx = br7(px);
  hp[px * NP + py] = make_float2(H[(ky * NP + kx) * 2 + 0] * INV_N2,
                                 H[(ky * NP + kx) * 2 + 1] * INV_N2);
}

// Per-n shift ramps at bit-reversed slot positions.
__global__ void __launch_bounds__(256) init_ramp(const float* __restrict__ shifts,
                                                 const int* __restrict__ indices,
                                                 float2* __restrict__ rampy,
                                                 float2* __restrict__ rampx) {
  int i = blockIdx.x * blockDim.x + threadIdx.x;
  if (i >= 2 * BATCH * NP) return;
  int which = (i >= BATCH * NP) ? 1 : 0;
  int r = i - which * BATCH * NP;
  int n = r >> 7, slot = r & (NP - 1);
  int pos = indices[n];
  float sh = shifts[2 * pos + which];
  int k = br7(slot);
  float f = (float)(k < 64 ? k : k - 128) * (1.f / 128.f);
  float s, c;
  __sincosf(-6.28318530717959f * f * sh, &s, &c);
  if (!which) rampy[n * NP + slot] = make_float2(c * INV_N2, s * INV_N2);
  else        rampx[n * NP + slot] = make_float2(c, s);
}

// Precompute T = obja * exp(i*objp) over the full object volume.
__global__ void __launch_bounds__(256) init_T(const float* __restrict__ obja,
                                              const float* __restrict__ objp,
                                              float2* __restrict__ T) {
  int i = blockIdx.x * 256 + threadIdx.x;
  if (i >= OMODE * NZ * NYX * NYX) return;
  float a = obja[i], ph = objp[i];
  float s, c;
  __sincosf(ph, &s, &c);
  T[i] = make_float2(a * c, a * s);
}

// Sum the 8 (o,p) partials per batch element. part tile is TRANSPOSED: [blk][kx][ky].
__global__ void __launch_bounds__(256) reduce_dp(const float* __restrict__ part,
                                                 float* __restrict__ dp) {
  int i = blockIdx.x * 256 + threadIdx.x;
  if (i >= BATCH * NP * NP) return;
  int n = i >> 14;
  int r = i & (NP * NP - 1);
  int ky = r >> 7, kx = r & (NP - 1);
  const float* b = part + ((size_t)n * 8 << 14) + (kx << 7) + ky;
  float s = 0.f;
#pragma unroll
  for (int j = 0; j < 8; ++j) s += b[(size_t)j << 14];
  dp[i] = s;
}

__global__ void __launch_bounds__(1024) ptycho_chain(
    const float* __restrict__ obja, const float* __restrict__ objp,
    const float* __restrict__ probe, const float* __restrict__ shifts,
    const float* __restrict__ H, const float2* __restrict__ hpre,
    const float2* __restrict__ rampy, const float2* __restrict__ rampx,
    const float2* __restrict__ Tpre,
    const float* __restrict__ occu, const int* __restrict__ indices,
    const int* __restrict__ crop, float* __restrict__ dp,
    float* __restrict__ part, int mode_ws, int mode_T)
{
  extern __shared__ v2f fld[];             // [128][LSTR] interleaved re/im

  const int blk  = blockIdx.x;             // n*8 + o*4 + p
  const int n    = blk >> 3;
  const int o    = (blk >> 2) & 1;
  const int p    = blk & 3;
  const int tid  = threadIdx.x;
  const int wid  = tid >> 6;               // 16 waves
  const int lane = tid & 63;

  const int   pos = indices[n];
  const int   cy  = crop[2 * pos + 0];
  const int   cx  = crop[2 * pos + 1];
  const float wocc = occu[o];

  // ---- twiddles (20 VGPRs) ----------------------------------------------
  Tw tw;
#pragma unroll
  for (int s = 0; s < 6; ++s) {
    int h = 1 << s;
    int j = lane & (h - 1);
    float ang = 3.14159265358979f * (float)j / (float)h;
    float ts_, tc_;
    __sincosf(ang, &ts_, &tc_);
    bool up = (lane >> s) & 1;
    tw.g[s]   = up ? -1.f : 1.f;
    tw.dwr[s] = up ? tc_ : 1.f;
    tw.dwi[s] = up ? -ts_ : 0.f;
  }
  __sincosf(3.14159265358979f * (float)lane * (1.f / 64.f), &tw.ts6, &tw.tc6);

  // ---- P0: load probe rows + forward row FFT ----------------------------
  const v2f* probe2 = (const v2f*)probe;
#pragma unroll 1
  for (int k0 = 0; k0 < 8; k0 += 2) {
    int r0 = wid * 8 + k0;
    v2f A0 = probe2[(p * NP + r0) * NP + lane];
    v2f B0 = probe2[(p * NP + r0) * NP + lane + 64];
    v2f A1 = probe2[(p * NP + r0 + 1) * NP + lane];
    v2f B1 = probe2[(p * NP + r0 + 1) * NP + lane + 64];
    dif128(A0, B0, tw, lane); dif128(A1, B1, tw, lane);
    fld[r0 * LSTR + lane]            = A0; fld[r0 * LSTR + lane + 64]       = B0;
    fld[(r0 + 1) * LSTR + lane]      = A1; fld[(r0 + 1) * LSTR + lane + 64] = B1;
  }
  __syncthreads();

  // fallback-only multiplies (no workspace): inline sincos / direct H
  auto ramp_mul_fb = [&](v2f& A, v2f& B, int c) {
    float sh0v = shifts[2 * pos], sh1v = shifts[2 * pos + 1];
    int kxc = br7(c);
    float fx = (float)(kxc < 64 ? kxc : kxc - 128) * (1.f / 128.f);
    int ky0 = br7(lane);
    float fy0 = (float)(ky0 < 64 ? ky0 : ky0 - 128) * (1.f / 128.f);
    int ky1 = ky0 + 1;
    float fy1 = (float)(ky1 < 64 ? ky1 : ky1 - 128) * (1.f / 128.f);
    float com = fx * sh1v;
    float s0, c0_, s1, c1_;
    __sincosf(-6.28318530717959f * (fy0 * sh0v + com), &s0, &c0_);
    __sincosf(-6.28318530717959f * (fy1 * sh0v + com), &s1, &c1_);
    A = cmulv(A, c0_ * INV_N2, s0 * INV_N2);
    B = cmulv(B, c1_ * INV_N2, s1 * INV_N2);
  };
  auto h_mul_fb = [&](v2f& A, v2f& B, int c) {
    int kx = br7(c), ky0 = br7(lane);
    float hr0 = H[(ky0 * NP + kx) * 2], hi0 = H[(ky0 * NP + kx) * 2 + 1];
    float hr1 = H[((ky0 + 1) * NP + kx) * 2], hi1 = H[((ky0 + 1) * NP + kx) * 2 + 1];
    A = cmulv(A, hr0 * INV_N2, hi0 * INV_N2);
    B = cmulv(B, hr1 * INV_N2, hi1 * INV_N2);
  };

  // ---- column phase: Fcol, freq multiply, invCol ------------------------
  auto cphase = [&](int mode) {
    v2f ry0, ry1;
    if (mode == 0 && mode_ws) {
      float2 t0 = rampy[n * NP + lane];
      float2 t1 = rampy[n * NP + lane + 64];
      ry0 = (v2f){t0.x, t0.y}; ry1 = (v2f){t1.x, t1.y};
    }
#pragma unroll 1
    for (int k0 = 0; k0 < 8; k0 += 2) {
      int c0 = wid * 8 + k0, c1 = c0 + 1;
      float2 h00, h01, h10, h11;
      if (mode == 1 && mode_ws) {
        h00 = hpre[c0 * NP + lane]; h01 = hpre[c0 * NP + lane + 64];
        h10 = hpre[c1 * NP + lane]; h11 = hpre[c1 * NP + lane + 64];
      }
      float2 rx0, rx1;
      if (mode == 0 && mode_ws) {
        rx0 = rampx[n * NP + c0]; rx1 = rampx[n * NP + c1];
      }
      v2f A0 = fld[lane * LSTR + c0], B0 = fld[(lane + 64) * LSTR + c0];
      v2f A1 = fld[lane * LSTR + c1], B1 = fld[(lane + 64) * LSTR + c1];
      dif128(A0, B0, tw, lane); dif128(A1, B1, tw, lane);
      if (mode == 0) {
        if (mode_ws) {
          v2f m;
          m = cmulv(ry0, rx0.x, rx0.y); A0 = cmulvv(A0, m);
          m = cmulv(ry1, rx0.x, rx0.y); B0 = cmulvv(B0, m);
          m = cmulv(ry0, rx1.x, rx1.y); A1 = cmulvv(A1, m);
          m = cmulv(ry1, rx1.x, rx1.y); B1 = cmulvv(B1, m);
        } else {
          ramp_mul_fb(A0, B0, c0);
          ramp_mul_fb(A1, B1, c1);
        }
      } else {
        if (mode_ws) {
          A0 = cmulv(A0, h00.x, h00.y); B0 = cmulv(B0, h01.x, h01.y);
          A1 = cmulv(A1, h10.x, h10.y); B1 = cmulv(B1, h11.x, h11.y);
        } else {
          h_mul_fb(A0, B0, c0);
          h_mul_fb(A1, B1, c1);
        }
      }
      dit128(A0, B0, tw, lane); dit128(A1, B1, tw, lane);
      fld[lane * LSTR + c0]        = A0; fld[(lane + 64) * LSTR + c0] = B0;
      fld[lane * LSTR + c1]        = A1; fld[(lane + 64) * LSTR + c1] = B1;
    }
    __syncthreads();
  };

  // ---- row phase: invRow, multiply T(z), Frow ---------------------------
  auto rphase = [&](int z) {
#pragma unroll 1
    for (int k0 = 0; k0 < 8; k0 += 2) {
      int r0 = wid * 8 + k0;
      size_t ob0 = ((size_t)(o * NZ + z) * NYX + (size_t)(cy + r0)) * NYX + cx;
      size_t ob1 = ob0 + NYX;
      v2f A0 = fld[r0 * LSTR + lane],       B0 = fld[r0 * LSTR + lane + 64];
      v2f A1 = fld[(r0 + 1) * LSTR + lane], B1 = fld[(r0 + 1) * LSTR + lane + 64];
      if (mode_T) {
        float2 t00 = Tpre[ob0 + lane], t01 = Tpre[ob0 + lane + 64];
        float2 t10 = Tpre[ob1 + lane], t11 = Tpre[ob1 + lane + 64];
        dit128(A0, B0, tw, lane); dit128(A1, B1, tw, lane);
        A0 = cmulv(A0, t00.x, t00.y); B0 = cmulv(B0, t01.x, t01.y);
        A1 = cmulv(A1, t10.x, t10.y); B1 = cmulv(B1, t11.x, t11.y);
      } else {
        float pa00 = obja[ob0 + lane],      ph00 = objp[ob0 + lane];
        float pa01 = obja[ob0 + lane + 64], ph01 = objp[ob0 + lane + 64];
        float pa10 = obja[ob1 + lane],      ph10 = objp[ob1 + lane];
        float pa11 = obja[ob1 + lane + 64], ph11 = objp[ob1 + lane + 64];
        dit128(A0, B0, tw, lane); dit128(A1, B1, tw, lane);
        float s, c;
        __sincosf(ph00, &s, &c); A0 = cmulv(A0, pa00 * c, pa00 * s);
        __sincosf(ph01, &s, &c); B0 = cmulv(B0, pa01 * c, pa01 * s);
        __sincosf(ph10, &s, &c); A1 = cmulv(A1, pa10 * c, pa10 * s);
        __sincosf(ph11, &s, &c); B1 = cmulv(B1, pa11 * c, pa11 * s);
      }
      dif128(A0, B0, tw, lane); dif128(A1, B1, tw, lane);
      fld[r0 * LSTR + lane]            = A0; fld[r0 * LSTR + lane + 64]       = B0;
      fld[(r0 + 1) * LSTR + lane]      = A1; fld[(r0 + 1) * LSTR + lane + 64] = B1;
    }
    __syncthreads();
  };

  cphase(0);        // Fcol + ramp + invCol  (completes probe shift)
  rphase(0);        // invRow + T0 + Frow
#pragma unroll 1
  for (int z = 1; z < NZ; ++z) {
    cphase(1);      // Fcol + H + invCol     (propagation z-1 -> z)
    rphase(z);      // invRow + Tz + Frow
  }

  // ---- final column FFT -> |.|^2 -> store (transposed part tile) --------
#pragma unroll 1
  for (int k0 = 0; k0 < 8; k0 += 2) {
    int c0 = wid * 8 + k0, c1 = c0 + 1;
    v2f A0 = fld[lane * LSTR + c0], B0 = fld[(lane + 64) * LSTR + c0];
    v2f A1 = fld[lane * LSTR + c1], B1 = fld[(lane + 64) * LSTR + c1];
    dif128(A0, B0, tw, lane); dif128(A1, B1, tw, lane);
    int ky0 = br7(lane);
    float m00 = (A0.x * A0.x + A0.y * A0.y) * wocc;
    float m01 = (B0.x * B0.x + B0.y * B0.y) * wocc;
    float m10 = (A1.x * A1.x + A1.y * A1.y) * wocc;
    float m11 = (B1.x * B1.x + B1.y * B1.y) * wocc;
    if (mode_ws) {
      size_t b0 = ((size_t)blk << 14) + (size_t)br7(c0) * NP;
      size_t b1 = ((size_t)blk << 14) + (size_t)br7(c1) * NP;
      part[b0 + ky0]     = m00;
      part[b0 + ky0 + 1] = m01;
      part[b1 + ky0]     = m10;
      part[b1 + ky0 + 1] = m11;
    } else {
      size_t base = ((size_t)n << 14);
      atomicAdd(&dp[base + (size_t)ky0 * NP + br7(c0)],       m00);
      atomicAdd(&dp[base + (size_t)(ky0 + 1) * NP + br7(c0)], m01);
      atomicAdd(&dp[base + (size_t)ky0 * NP + br7(c1)],       m10);
      atomicAdd(&dp[base + (size_t)(ky0 + 1) * NP + br7(c1)], m11);
    }
  }
}

extern "C" void kernel_launch(void* const* d_in, const int* in_sizes, int n_in,
                              void* d_out, int out_size, void* d_ws, size_t ws_size,
                              hipStream_t stream) {
  const float* obja   = (const float*)d_in[0];
  const float* objp   = (const float*)d_in[1];
  const float* probe  = (const float*)d_in[2];
  const float* shifts = (const float*)d_in[3];
  const float* H      = (const float*)d_in[4];
  const float* occu   = (const float*)d_in[5];
  const int*   indices = (const int*)d_in[6];
  const int*   crop    = (const int*)d_in[7];
  float* dp = (float*)d_out;

  const size_t part_bytes  = (size_t)BATCH * OMODE * PMODE * NP * NP * sizeof(float); // 32 MB
  const size_t hpre_bytes  = (size_t)NP * NP * sizeof(float2);                        // 128 KB
  const size_t ramp_bytes  = (size_t)BATCH * NP * sizeof(float2);                     // 64 KB each
  const size_t T_bytes     = (size_t)OMODE * NZ * NYX * NYX * sizeof(float2);         // 33.5 MB
  const size_t need_ws = part_bytes + hpre_bytes + 2 * ramp_bytes;
  const size_t need_T  = need_ws + T_bytes;

  int mode_ws = (ws_size >= need_ws) ? 1 : 0;
  int mode_T  = (ws_size >= need_T) ? 1 : 0;
  float*  part  = (float*)d_ws;
  float2* hpre  = (float2*)((char*)d_ws + part_bytes);
  float2* rampy = (float2*)((char*)d_ws + part_bytes + hpre_bytes);
  float2* rampx = (float2*)((char*)d_ws + part_bytes + hpre_bytes + ramp_bytes);
  float2* Tpre  = (float2*)((char*)d_ws + need_ws);

  if (mode_ws) {
    hipLaunchKernelGGL(init_hpre, dim3((NP * NP + 255) / 256), dim3(256), 0,
                       stream, H, hpre);
    hipLaunchKernelGGL(init_ramp, dim3((2 * BATCH * NP + 255) / 256), dim3(256), 0,
                       stream, shifts, indices, rampy, rampx);
  } else {
    // atomic fallback accumulates -> must zero output every call
    hipMemsetAsync(d_out, 0, (size_t)out_size * sizeof(float), stream);
  }
  if (mode_T) {
    hipLaunchKernelGGL(init_T, dim3((OMODE * NZ * NYX * NYX + 255) / 256), dim3(256),
                       0, stream, obja, objp, Tpre);
  }

  const int lds_bytes = NP * LSTR * (int)sizeof(float2);  // 132096
  hipFuncSetAttribute((const void*)ptycho_chain,
                      hipFuncAttributeMaxDynamicSharedMemorySize, lds_bytes);
  hipLaunchKernelGGL(ptycho_chain, dim3(BATCH * OMODE * PMODE), dim3(1024),
                     lds_bytes, stream,
                     obja, objp, probe, shifts, H, hpre, rampy, rampx, Tpre,
                     occu, indices, crop, dp, part, mode_ws, mode_T);
  if (mode_ws) {
    hipLaunchKernelGGL(reduce_dp, dim3((BATCH * NP * NP + 255) / 256), dim3(256),
                       0, stream, part, dp);
  }
}

// Round 7
// 388.348 us; speedup vs baseline: 1.5668x; 1.2963x over previous
//
#include <hip/hip_runtime.h>

// ---- problem constants --------------------------------------------------
static constexpr int OMODE = 2, PMODE = 4, NZ = 8;
static constexpr int NYX = 512;   // object plane 512x512
static constexpr int NP  = 128;   // probe / tile 128x128
static constexpr int BATCH = 64;
static constexpr int LSTR = 129;  // padded LDS line stride (float2 units)
static constexpr float INV_N2 = 1.0f / 16384.0f;   // 1/(128*128) ifft2 norm

typedef float v2f __attribute__((ext_vector_type(2)));

__device__ __forceinline__ int br7(int x) { return (int)(__brev((unsigned)x) >> 25); }

__device__ __forceinline__ v2f splat2(float s) { return (v2f){s, s}; }
__device__ __forceinline__ v2f swapv(v2f v) { return __builtin_shufflevector(v, v, 1, 0); }
__device__ __forceinline__ v2f cmulv(v2f a, float br_, float bi_) {
  return a * splat2(br_) + swapv(a) * (v2f){-bi_, bi_};
}
__device__ __forceinline__ v2f cmulvv(v2f a, v2f b) {
  return a * splat2(b.x) + swapv(a) * (v2f){-b.y, b.y};
}

// ---- cross-lane exchange ------------------------------------------------
template<int CTRL>
__device__ __forceinline__ float dppf(float x) {
  int i = __float_as_int(x);
  int r = __builtin_amdgcn_update_dpp(i, i, CTRL, 0xF, 0xF, false);
  return __int_as_float(r);
}

// Per-thread twiddles, scalars only (compile-time indexed) -> VGPRs.
// Stage 0 twiddle is identity -> dwr/dwi[0] unused (specialized stage).
struct Tw {
  float tc6, ts6;            // cos/sin(pi*lane/64) for the register stage
  float g[6];                // +1 lower lane of pair, -1 upper
  float dwr[6], dwi[6];      // DIF post-mul: up ? conj(w) : 1   (DIT uses dwr,-dwi)
};

// butterfly d = partner + g*own, via DPP (H=1,2)
template<int CTRL, int S>
__device__ __forceinline__ v2f bfly_dpp(v2f m, const Tw& tw) {
  v2f t = (v2f){dppf<CTRL>(m.x), dppf<CTRL>(m.y)};
  return t + splat2(tw.g[S]) * m;
}
// butterfly via ds_swizzle (H=4,8,16): OFS = (H<<10)|0x1F
template<int OFS, int S>
__device__ __forceinline__ v2f bfly_swz(v2f m, const Tw& tw) {
  v2f t;
  t.x = __int_as_float(__builtin_amdgcn_ds_swizzle(__float_as_int(m.x), OFS));
  t.y = __int_as_float(__builtin_amdgcn_ds_swizzle(__float_as_int(m.y), OFS));
  return t + splat2(tw.g[S]) * m;
}
// butterfly via permlane32_swap (H=32).
// r0 = (lower? own : partner), r1 = (lower? partner : own)  [validated R4]
// d = partner + g*own = r0 + g*r1 for both halves (g=+1 lower, -1 upper).
__device__ __forceinline__ v2f bfly_pl32(v2f m, float g5) {
#if __has_builtin(__builtin_amdgcn_permlane32_swap)
  auto rx = __builtin_amdgcn_permlane32_swap(__float_as_uint(m.x), __float_as_uint(m.x), false, false);
  auto ry = __builtin_amdgcn_permlane32_swap(__float_as_uint(m.y), __float_as_uint(m.y), false, false);
  v2f d;
  d.x = fmaf(g5, __uint_as_float(rx[1]), __uint_as_float(rx[0]));
  d.y = fmaf(g5, __uint_as_float(ry[1]), __uint_as_float(ry[0]));
  return d;
#else
  v2f t = (v2f){__shfl_xor(m.x, 32), __shfl_xor(m.y, 32)};
  return t + splat2(g5) * m;
#endif
}

template<int S> __device__ __forceinline__ v2f twd(v2f d, const Tw& tw) {  // dif post-mul
  return d * splat2(tw.dwr[S]) + swapv(d) * (v2f){-tw.dwi[S], tw.dwi[S]};
}
template<int S> __device__ __forceinline__ v2f twc(v2f a, const Tw& tw) {  // dit pre-mul (conj)
  return a * splat2(tw.dwr[S]) + swapv(a) * (v2f){tw.dwi[S], -tw.dwi[S]};
}

// Forward 128-pt DIF: natural-order input -> bit-reversed-order slots.
__device__ __forceinline__ void dif128(v2f& A, v2f& B, const Tw& tw) {
  { // register stage h=64: w = e^{-i*pi*lane/64}
    v2f d = A - B;
    A = A + B;
    B = d * splat2(tw.tc6) + swapv(d) * (v2f){tw.ts6, -tw.ts6};
  }
  A = twd<5>(bfly_pl32(A, tw.g[5]), tw);        B = twd<5>(bfly_pl32(B, tw.g[5]), tw);
  A = twd<4>(bfly_swz<0x401F, 4>(A, tw), tw);   B = twd<4>(bfly_swz<0x401F, 4>(B, tw), tw);
  A = twd<3>(bfly_swz<0x201F, 3>(A, tw), tw);   B = twd<3>(bfly_swz<0x201F, 3>(B, tw), tw);
  A = twd<2>(bfly_swz<0x101F, 2>(A, tw), tw);   B = twd<2>(bfly_swz<0x101F, 2>(B, tw), tw);
  A = twd<1>(bfly_dpp<0x4E, 1>(A, tw), tw);     B = twd<1>(bfly_dpp<0x4E, 1>(B, tw), tw);
  A = bfly_dpp<0xB1, 0>(A, tw);                 B = bfly_dpp<0xB1, 0>(B, tw);   // stage 0: w=1
}

// Inverse (unnormalized) 128-pt DIT: bit-reversed slots -> natural order.
__device__ __forceinline__ void dit128(v2f& A, v2f& B, const Tw& tw) {
  A = bfly_dpp<0xB1, 0>(A, tw);                 B = bfly_dpp<0xB1, 0>(B, tw);   // stage 0: w=1
  A = bfly_dpp<0x4E, 1>(twc<1>(A, tw), tw);     B = bfly_dpp<0x4E, 1>(twc<1>(B, tw), tw);
  A = bfly_swz<0x101F, 2>(twc<2>(A, tw), tw);   B = bfly_swz<0x101F, 2>(twc<2>(B, tw), tw);
  A = bfly_swz<0x201F, 3>(twc<3>(A, tw), tw);   B = bfly_swz<0x201F, 3>(twc<3>(B, tw), tw);
  A = bfly_swz<0x401F, 4>(twc<4>(A, tw), tw);   B = bfly_swz<0x401F, 4>(twc<4>(B, tw), tw);
  A = bfly_pl32(twc<5>(A, tw), tw.g[5]);        B = bfly_pl32(twc<5>(B, tw), tw.g[5]);
  { // register stage h=64: w = e^{+i*pi*lane/64}
    v2f m = B * splat2(tw.tc6) + swapv(B) * (v2f){-tw.ts6, tw.ts6};
    B = A - m;
    A = A + m;
  }
}

// Pre-scramble H into workspace: hp[px][py] = H[br(py)][br(px)] * (1/N^2).
__global__ void __launch_bounds__(256) init_hpre(const float* __restrict__ H,
                                                 float2* __restrict__ hp) {
  int i = blockIdx.x * blockDim.x + threadIdx.x;
  if (i >= NP * NP) return;
  int px = i >> 7, py = i & (NP - 1);
  int ky = br7(py), kx = br7(px);
  hp[px * NP + py] = make_float2(H[(ky * NP + kx) * 2 + 0] * INV_N2,
                                 H[(ky * NP + kx) * 2 + 1] * INV_N2);
}

// Per-n shift ramps at bit-reversed slot positions.
__global__ void __launch_bounds__(256) init_ramp(const float* __restrict__ shifts,
                                                 const int* __restrict__ indices,
                                                 float2* __restrict__ rampy,
                                                 float2* __restrict__ rampx) {
  int i = blockIdx.x * blockDim.x + threadIdx.x;
  if (i >= 2 * BATCH * NP) return;
  int which = (i >= BATCH * NP) ? 1 : 0;
  int r = i - which * BATCH * NP;
  int n = r >> 7, slot = r & (NP - 1);
  int pos = indices[n];
  float sh = shifts[2 * pos + which];
  int k = br7(slot);
  float f = (float)(k < 64 ? k : k - 128) * (1.f / 128.f);
  float s, c;
  __sincosf(-6.28318530717959f * f * sh, &s, &c);
  if (!which) rampy[n * NP + slot] = make_float2(c * INV_N2, s * INV_N2);
  else        rampx[n * NP + slot] = make_float2(c, s);
}

// Precompute T = obja * exp(i*objp) over the full object volume.
__global__ void __launch_bounds__(256) init_T(const float* __restrict__ obja,
                                              const float* __restrict__ objp,
                                              float2* __restrict__ T) {
  int i = blockIdx.x * 256 + threadIdx.x;
  if (i >= OMODE * NZ * NYX * NYX) return;
  float a = obja[i], ph = objp[i];
  float s, c;
  __sincosf(ph, &s, &c);
  T[i] = make_float2(a * c, a * s);
}

// Sum the 8 (o,p) partials per batch element, applying omode occupancy here.
// part tile is TRANSPOSED: [blk][kx][ky].
__global__ void __launch_bounds__(256) reduce_dp(const float* __restrict__ part,
                                                 const float* __restrict__ occu,
                                                 float* __restrict__ dp) {
  int i = blockIdx.x * 256 + threadIdx.x;
  if (i >= BATCH * NP * NP) return;
  int n = i >> 14;
  int r = i & (NP * NP - 1);
  int ky = r >> 7, kx = r & (NP - 1);
  const float* b = part + ((size_t)n * 8 << 14) + (kx << 7) + ky;
  float w0 = occu[0], w1 = occu[1];
  float s = 0.f;
#pragma unroll
  for (int j = 0; j < 8; ++j) s = fmaf(b[(size_t)j << 14], (j < 4 ? w0 : w1), s);
  dp[i] = s;
}

__global__ void __launch_bounds__(1024) ptycho_chain(
    const float* __restrict__ obja, const float* __restrict__ objp,
    const float* __restrict__ probe, const float* __restrict__ shifts,
    const float* __restrict__ H, const float2* __restrict__ hpre,
    const float2* __restrict__ rampy, const float2* __restrict__ rampx,
    const float2* __restrict__ Tpre,
    const float* __restrict__ occu, const int* __restrict__ indices,
    const int* __restrict__ crop, float* __restrict__ dp,
    float* __restrict__ part, int mode_ws, int mode_T)
{
  extern __shared__ v2f fld[];             // [128][LSTR] interleaved re/im

  const int blk  = blockIdx.x;             // n*8 + o*4 + p
  const int n    = blk >> 3;
  const int o    = (blk >> 2) & 1;
  const int p    = blk & 3;
  const int tid  = threadIdx.x;
  const int wid  = tid >> 6;               // 16 waves
  const int lane = tid & 63;

  const int   pos = indices[n];
  const int   cy  = crop[2 * pos + 0];
  const int   cx  = crop[2 * pos + 1];
  const float wocc = occu[o];

  // ---- twiddles ----------------------------------------------------------
  Tw tw;
  tw.g[0] = ((lane >> 0) & 1) ? -1.f : 1.f;
#pragma unroll
  for (int s = 1; s < 6; ++s) {
    int h = 1 << s;
    int j = lane & (h - 1);
    float ang = 3.14159265358979f * (float)j / (float)h;
    float ts_, tc_;
    __sincosf(ang, &ts_, &tc_);
    bool up = (lane >> s) & 1;
    tw.g[s]   = up ? -1.f : 1.f;
    tw.dwr[s] = up ? tc_ : 1.f;
    tw.dwi[s] = up ? -ts_ : 0.f;
  }
  __sincosf(3.14159265358979f * (float)lane * (1.f / 64.f), &tw.ts6, &tw.tc6);

  // ---- P0: load probe rows + forward row FFT ----------------------------
  const v2f* probe2 = (const v2f*)probe;
#pragma unroll 1
  for (int k0 = 0; k0 < 8; k0 += 2) {
    int r0 = wid * 8 + k0;
    v2f A0 = probe2[(p * NP + r0) * NP + lane];
    v2f B0 = probe2[(p * NP + r0) * NP + lane + 64];
    v2f A1 = probe2[(p * NP + r0 + 1) * NP + lane];
    v2f B1 = probe2[(p * NP + r0 + 1) * NP + lane + 64];
    dif128(A0, B0, tw); dif128(A1, B1, tw);
    fld[r0 * LSTR + lane]            = A0; fld[r0 * LSTR + lane + 64]       = B0;
    fld[(r0 + 1) * LSTR + lane]      = A1; fld[(r0 + 1) * LSTR + lane + 64] = B1;
  }
  __syncthreads();

  // fallback-only multiplies (no workspace)
  auto ramp_mul_fb = [&](v2f& A, v2f& B, int c) {
    float sh0v = shifts[2 * pos], sh1v = shifts[2 * pos + 1];
    int kxc = br7(c);
    float fx = (float)(kxc < 64 ? kxc : kxc - 128) * (1.f / 128.f);
    int ky0 = br7(lane);
    float fy0 = (float)(ky0 < 64 ? ky0 : ky0 - 128) * (1.f / 128.f);
    int ky1 = ky0 + 1;
    float fy1 = (float)(ky1 < 64 ? ky1 : ky1 - 128) * (1.f / 128.f);
    float com = fx * sh1v;
    float s0, c0_, s1, c1_;
    __sincosf(-6.28318530717959f * (fy0 * sh0v + com), &s0, &c0_);
    __sincosf(-6.28318530717959f * (fy1 * sh0v + com), &s1, &c1_);
    A = cmulv(A, c0_ * INV_N2, s0 * INV_N2);
    B = cmulv(B, c1_ * INV_N2, s1 * INV_N2);
  };
  auto h_mul_fb = [&](v2f& A, v2f& B, int c) {
    int kx = br7(c), ky0 = br7(lane);
    float hr0 = H[(ky0 * NP + kx) * 2], hi0 = H[(ky0 * NP + kx) * 2 + 1];
    float hr1 = H[((ky0 + 1) * NP + kx) * 2], hi1 = H[((ky0 + 1) * NP + kx) * 2 + 1];
    A = cmulv(A, hr0 * INV_N2, hi0 * INV_N2);
    B = cmulv(B, hr1 * INV_N2, hi1 * INV_N2);
  };

  // ---- column phase: Fcol, freq multiply, invCol ------------------------
  auto cphase = [&](int mode) {
    v2f ry0, ry1;
    if (mode == 0 && mode_ws) {
      float2 t0 = rampy[n * NP + lane];
      float2 t1 = rampy[n * NP + lane + 64];
      ry0 = (v2f){t0.x, t0.y}; ry1 = (v2f){t1.x, t1.y};
    }
#pragma unroll 1
    for (int k0 = 0; k0 < 8; k0 += 2) {
      int c0 = wid * 8 + k0, c1 = c0 + 1;
      float2 h00, h01, h10, h11;
      if (mode == 1 && mode_ws) {
        h00 = hpre[c0 * NP + lane]; h01 = hpre[c0 * NP + lane + 64];
        h10 = hpre[c1 * NP + lane]; h11 = hpre[c1 * NP + lane + 64];
      }
      float2 rx0, rx1;
      if (mode == 0 && mode_ws) {
        rx0 = rampx[n * NP + c0]; rx1 = rampx[n * NP + c1];
      }
      v2f A0 = fld[lane * LSTR + c0], B0 = fld[(lane + 64) * LSTR + c0];
      v2f A1 = fld[lane * LSTR + c1], B1 = fld[(lane + 64) * LSTR + c1];
      dif128(A0, B0, tw); dif128(A1, B1, tw);
      if (mode == 0) {
        if (mode_ws) {
          v2f m;
          m = cmulv(ry0, rx0.x, rx0.y); A0 = cmulvv(A0, m);
          m = cmulv(ry1, rx0.x, rx0.y); B0 = cmulvv(B0, m);
          m = cmulv(ry0, rx1.x, rx1.y); A1 = cmulvv(A1, m);
          m = cmulv(ry1, rx1.x, rx1.y); B1 = cmulvv(B1, m);
        } else {
          ramp_mul_fb(A0, B0, c0);
          ramp_mul_fb(A1, B1, c1);
        }
      } else {
        if (mode_ws) {
          A0 = cmulv(A0, h00.x, h00.y); B0 = cmulv(B0, h01.x, h01.y);
          A1 = cmulv(A1, h10.x, h10.y); B1 = cmulv(B1, h11.x, h11.y);
        } else {
          h_mul_fb(A0, B0, c0);
          h_mul_fb(A1, B1, c1);
        }
      }
      dit128(A0, B0, tw); dit128(A1, B1, tw);
      fld[lane * LSTR + c0]        = A0; fld[(lane + 64) * LSTR + c0] = B0;
      fld[lane * LSTR + c1]        = A1; fld[(lane + 64) * LSTR + c1] = B1;
    }
    __syncthreads();
  };

  // ---- row phase: invRow, multiply T(z), Frow ---------------------------
  auto rphase = [&](int z) {
#pragma unroll 1
    for (int k0 = 0; k0 < 8; k0 += 2) {
      int r0 = wid * 8 + k0;
      size_t ob0 = ((size_t)(o * NZ + z) * NYX + (size_t)(cy + r0)) * NYX + cx;
      size_t ob1 = ob0 + NYX;
      v2f A0 = fld[r0 * LSTR + lane],       B0 = fld[r0 * LSTR + lane + 64];
      v2f A1 = fld[(r0 + 1) * LSTR + lane], B1 = fld[(r0 + 1) * LSTR + lane + 64];
      if (mode_T) {
        float2 t00 = Tpre[ob0 + lane], t01 = Tpre[ob0 + lane + 64];
        float2 t10 = Tpre[ob1 + lane], t11 = Tpre[ob1 + lane + 64];
        dit128(A0, B0, tw); dit128(A1, B1, tw);
        A0 = cmulv(A0, t00.x, t00.y); B0 = cmulv(B0, t01.x, t01.y);
        A1 = cmulv(A1, t10.x, t10.y); B1 = cmulv(B1, t11.x, t11.y);
      } else {
        float pa00 = obja[ob0 + lane],      ph00 = objp[ob0 + lane];
        float pa01 = obja[ob0 + lane + 64], ph01 = objp[ob0 + lane + 64];
        float pa10 = obja[ob1 + lane],      ph10 = objp[ob1 + lane];
        float pa11 = obja[ob1 + lane + 64], ph11 = objp[ob1 + lane + 64];
        dit128(A0, B0, tw); dit128(A1, B1, tw);
        float s, c;
        __sincosf(ph00, &s, &c); A0 = cmulv(A0, pa00 * c, pa00 * s);
        __sincosf(ph01, &s, &c); B0 = cmulv(B0, pa01 * c, pa01 * s);
        __sincosf(ph10, &s, &c); A1 = cmulv(A1, pa10 * c, pa10 * s);
        __sincosf(ph11, &s, &c); B1 = cmulv(B1, pa11 * c, pa11 * s);
      }
      dif128(A0, B0, tw); dif128(A1, B1, tw);
      fld[r0 * LSTR + lane]            = A0; fld[r0 * LSTR + lane + 64]       = B0;
      fld[(r0 + 1) * LSTR + lane]      = A1; fld[(r0 + 1) * LSTR + lane + 64] = B1;
    }
    __syncthreads();
  };

  cphase(0);        // Fcol + ramp + invCol  (completes probe shift)
  rphase(0);        // invRow + T0 + Frow
#pragma unroll 1
  for (int z = 1; z < NZ; ++z) {
    cphase(1);      // Fcol + H + invCol     (propagation z-1 -> z)
    rphase(z);      // invRow + Tz + Frow
  }

  // ---- final column FFT -> |.|^2 -> store (transposed part tile) --------
#pragma unroll 1
  for (int k0 = 0; k0 < 8; k0 += 2) {
    int c0 = wid * 8 + k0, c1 = c0 + 1;
    v2f A0 = fld[lane * LSTR + c0], B0 = fld[(lane + 64) * LSTR + c0];
    v2f A1 = fld[lane * LSTR + c1], B1 = fld[(lane + 64) * LSTR + c1];
    dif128(A0, B0, tw); dif128(A1, B1, tw);
    int ky0 = br7(lane);
    float m00 = fmaf(A0.x, A0.x, A0.y * A0.y);
    float m01 = fmaf(B0.x, B0.x, B0.y * B0.y);
    float m10 = fmaf(A1.x, A1.x, A1.y * A1.y);
    float m11 = fmaf(B1.x, B1.x, B1.y * B1.y);
    if (mode_ws) {
      size_t b0 = ((size_t)blk << 14) + (size_t)br7(c0) * NP;
      size_t b1 = ((size_t)blk << 14) + (size_t)br7(c1) * NP;
      part[b0 + ky0]     = m00;     // occupancy weight applied in reduce_dp
      part[b0 + ky0 + 1] = m01;
      part[b1 + ky0]     = m10;
      part[b1 + ky0 + 1] = m11;
    } else {
      size_t base = ((size_t)n << 14);
      atomicAdd(&dp[base + (size_t)ky0 * NP + br7(c0)],       m00 * wocc);
      atomicAdd(&dp[base + (size_t)(ky0 + 1) * NP + br7(c0)], m01 * wocc);
      atomicAdd(&dp[base + (size_t)ky0 * NP + br7(c1)],       m10 * wocc);
      atomicAdd(&dp[base + (size_t)(ky0 + 1) * NP + br7(c1)], m11 * wocc);
    }
  }
}

extern "C" void kernel_launch(void* const* d_in, const int* in_sizes, int n_in,
                              void* d_out, int out_size, void* d_ws, size_t ws_size,
                              hipStream_t stream) {
  const float* obja   = (const float*)d_in[0];
  const float* objp   = (const float*)d_in[1];
  const float* probe  = (const float*)d_in[2];
  const float* shifts = (const float*)d_in[3];
  const float* H      = (const float*)d_in[4];
  const float* occu   = (const float*)d_in[5];
  const int*   indices = (const int*)d_in[6];
  const int*   crop    = (const int*)d_in[7];
  float* dp = (float*)d_out;

  const size_t part_bytes  = (size_t)BATCH * OMODE * PMODE * NP * NP * sizeof(float); // 32 MB
  const size_t hpre_bytes  = (size_t)NP * NP * sizeof(float2);                        // 128 KB
  const size_t ramp_bytes  = (size_t)BATCH * NP * sizeof(float2);                     // 64 KB each
  const size_t T_bytes     = (size_t)OMODE * NZ * NYX * NYX * sizeof(float2);         // 33.5 MB
  const size_t need_ws = part_bytes + hpre_bytes + 2 * ramp_bytes;
  const size_t need_T  = need_ws + T_bytes;

  int mode_ws = (ws_size >= need_ws) ? 1 : 0;
  int mode_T  = (ws_size >= need_T) ? 1 : 0;
  float*  part  = (float*)d_ws;
  float2* hpre  = (float2*)((char*)d_ws + part_bytes);
  float2* rampy = (float2*)((char*)d_ws + part_bytes + hpre_bytes);
  float2* rampx = (float2*)((char*)d_ws + part_bytes + hpre_bytes + ramp_bytes);
  float2* Tpre  = (float2*)((char*)d_ws + need_ws);

  if (mode_ws) {
    hipLaunchKernelGGL(init_hpre, dim3((NP * NP + 255) / 256), dim3(256), 0,
                       stream, H, hpre);
    hipLaunchKernelGGL(init_ramp, dim3((2 * BATCH * NP + 255) / 256), dim3(256), 0,
                       stream, shifts, indices, rampy, rampx);
  } else {
    // atomic fallback accumulates -> must zero output every call
    hipMemsetAsync(d_out, 0, (size_t)out_size * sizeof(float), stream);
  }
  if (mode_T) {
    hipLaunchKernelGGL(init_T, dim3((OMODE * NZ * NYX * NYX + 255) / 256), dim3(256),
                       0, stream, obja, objp, Tpre);
  }

  const int lds_bytes = NP * LSTR * (int)sizeof(float2);  // 132096
  hipFuncSetAttribute((const void*)ptycho_chain,
                      hipFuncAttributeMaxDynamicSharedMemorySize, lds_bytes);
  hipLaunchKernelGGL(ptycho_chain, dim3(BATCH * OMODE * PMODE), dim3(1024),
                     lds_bytes, stream,
                     obja, objp, probe, shifts, H, hpre, rampy, rampx, Tpre,
                     occu, indices, crop, dp, part, mode_ws, mode_T);
  if (mode_ws) {
    hipLaunchKernelGGL(reduce_dp, dim3((BATCH * NP * NP + 255) / 256), dim3(256),
                       0, stream, part, occu, dp);
  }
}

// Round 8
// 387.483 us; speedup vs baseline: 1.5703x; 1.0022x over previous
//
#include <hip/hip_runtime.h>

// ---- problem constants --------------------------------------------------
static constexpr int OMODE = 2, PMODE = 4, NZ = 8;
static constexpr int NYX = 512;   // object plane 512x512
static constexpr int NP  = 128;   // probe / tile 128x128
static constexpr int BATCH = 64;
static constexpr int LSTR = 129;  // padded LDS line stride (float2 units)
static constexpr float INV_N2 = 1.0f / 16384.0f;   // 1/(128*128) ifft2 norm

typedef float v2f __attribute__((ext_vector_type(2)));

__device__ __forceinline__ int br7(int x) { return (int)(__brev((unsigned)x) >> 25); }

__device__ __forceinline__ v2f splat2(float s) { return (v2f){s, s}; }
__device__ __forceinline__ v2f swapv(v2f v) { return __builtin_shufflevector(v, v, 1, 0); }
__device__ __forceinline__ v2f cmulv(v2f a, float br_, float bi_) {
  return a * splat2(br_) + swapv(a) * (v2f){-bi_, bi_};
}
__device__ __forceinline__ v2f cmulvv(v2f a, v2f b) {
  return a * splat2(b.x) + swapv(a) * (v2f){-b.y, b.y};
}

// ---- cross-lane exchange ------------------------------------------------
template<int CTRL>
__device__ __forceinline__ float dppf(float x) {
  int i = __float_as_int(x);
  int r = __builtin_amdgcn_update_dpp(i, i, CTRL, 0xF, 0xF, false);
  return __int_as_float(r);
}

// Per-thread twiddles, scalars only (compile-time indexed) -> VGPRs.
struct Tw {
  float tc6, ts6;            // cos/sin(pi*lane/64) for the register stage
  float g[6];                // +1 lower lane of pair, -1 upper
  float dwr[6], dwi[6];      // DIF post-mul: up ? conj(w) : 1   (DIT uses dwr,-dwi)
};

// butterfly d = partner + g*own, via DPP (H=2)
template<int CTRL, int S>
__device__ __forceinline__ v2f bfly_dpp(v2f m, const Tw& tw) {
  v2f t = (v2f){dppf<CTRL>(m.x), dppf<CTRL>(m.y)};
  return t + splat2(tw.g[S]) * m;
}
// butterfly via ds_swizzle (H=1,4,8,16): OFS = (H<<10)|0x1F
template<int OFS, int S>
__device__ __forceinline__ v2f bfly_swz(v2f m, const Tw& tw) {
  v2f t;
  t.x = __int_as_float(__builtin_amdgcn_ds_swizzle(__float_as_int(m.x), OFS));
  t.y = __int_as_float(__builtin_amdgcn_ds_swizzle(__float_as_int(m.y), OFS));
  return t + splat2(tw.g[S]) * m;
}
// butterfly via ds_bpermute (H=32): bp32 = (lane^32)<<2, full-wave64 permute
__device__ __forceinline__ v2f bfly_bp32(v2f m, int bp32, float g5) {
  v2f t;
  t.x = __int_as_float(__builtin_amdgcn_ds_bpermute(bp32, __float_as_int(m.x)));
  t.y = __int_as_float(__builtin_amdgcn_ds_bpermute(bp32, __float_as_int(m.y)));
  return t + splat2(g5) * m;
}

template<int S> __device__ __forceinline__ v2f twd(v2f d, const Tw& tw) {  // dif post-mul
  return d * splat2(tw.dwr[S]) + swapv(d) * (v2f){-tw.dwi[S], tw.dwi[S]};
}
template<int S> __device__ __forceinline__ v2f twc(v2f a, const Tw& tw) {  // dit pre-mul (conj)
  return a * splat2(tw.dwr[S]) + swapv(a) * (v2f){tw.dwi[S], -tw.dwi[S]};
}

// Forward 128-pt DIF: natural-order input -> bit-reversed-order slots.
__device__ __forceinline__ void dif128(v2f& A, v2f& B, const Tw& tw, int bp32) {
  { // register stage h=64: w = e^{-i*pi*lane/64}
    v2f d = A - B;
    A = A + B;
    B = d * splat2(tw.tc6) + swapv(d) * (v2f){tw.ts6, -tw.ts6};
  }
  A = twd<5>(bfly_bp32(A, bp32, tw.g[5]), tw);  B = twd<5>(bfly_bp32(B, bp32, tw.g[5]), tw);
  A = twd<4>(bfly_swz<0x401F, 4>(A, tw), tw);   B = twd<4>(bfly_swz<0x401F, 4>(B, tw), tw);
  A = twd<3>(bfly_swz<0x201F, 3>(A, tw), tw);   B = twd<3>(bfly_swz<0x201F, 3>(B, tw), tw);
  A = twd<2>(bfly_swz<0x101F, 2>(A, tw), tw);   B = twd<2>(bfly_swz<0x101F, 2>(B, tw), tw);
  A = twd<1>(bfly_dpp<0x4E, 1>(A, tw), tw);     B = twd<1>(bfly_dpp<0x4E, 1>(B, tw), tw);
  A = bfly_swz<0x041F, 0>(A, tw);               B = bfly_swz<0x041F, 0>(B, tw);  // stage 0: w=1
}

// Inverse (unnormalized) 128-pt DIT: bit-reversed slots -> natural order.
__device__ __forceinline__ void dit128(v2f& A, v2f& B, const Tw& tw, int bp32) {
  A = bfly_swz<0x041F, 0>(A, tw);               B = bfly_swz<0x041F, 0>(B, tw);  // stage 0: w=1
  A = bfly_dpp<0x4E, 1>(twc<1>(A, tw), tw);     B = bfly_dpp<0x4E, 1>(twc<1>(B, tw), tw);
  A = bfly_swz<0x101F, 2>(twc<2>(A, tw), tw);   B = bfly_swz<0x101F, 2>(twc<2>(B, tw), tw);
  A = bfly_swz<0x201F, 3>(twc<3>(A, tw), tw);   B = bfly_swz<0x201F, 3>(twc<3>(B, tw), tw);
  A = bfly_swz<0x401F, 4>(twc<4>(A, tw), tw);   B = bfly_swz<0x401F, 4>(twc<4>(B, tw), tw);
  A = bfly_bp32(twc<5>(A, tw), bp32, tw.g[5]);  B = bfly_bp32(twc<5>(B, tw), bp32, tw.g[5]);
  { // register stage h=64: w = e^{+i*pi*lane/64}
    v2f m = B * splat2(tw.tc6) + swapv(B) * (v2f){-tw.ts6, tw.ts6};
    B = A - m;
    A = A + m;
  }
}

// Pre-scramble H into workspace: hp[px][py] = H[br(py)][br(px)] * (1/N^2).
__global__ void __launch_bounds__(256) init_hpre(const float* __restrict__ H,
                                                 float2* __restrict__ hp) {
  int i = blockIdx.x * blockDim.x + threadIdx.x;
  if (i >= NP * NP) return;
  int px = i >> 7, py = i & (NP - 1);
  int ky = br7(py), kx = br7(px);
  hp[px * NP + py] = make_float2(H[(ky * NP + kx) * 2 + 0] * INV_N2,
                                 H[(ky * NP + kx) * 2 + 1] * INV_N2);
}

// Per-n shift ramps at bit-reversed slot positions.
__global__ void __launch_bounds__(256) init_ramp(const float* __restrict__ shifts,
                                                 const int* __restrict__ indices,
                                                 float2* __restrict__ rampy,
                                                 float2* __restrict__ rampx) {
  int i = blockIdx.x * blockDim.x + threadIdx.x;
  if (i >= 2 * BATCH * NP) return;
  int which = (i >= BATCH * NP) ? 1 : 0;
  int r = i - which * BATCH * NP;
  int n = r >> 7, slot = r & (NP - 1);
  int pos = indices[n];
  float sh = shifts[2 * pos + which];
  int k = br7(slot);
  float f = (float)(k < 64 ? k : k - 128) * (1.f / 128.f);
  float s, c;
  __sincosf(-6.28318530717959f * f * sh, &s, &c);
  if (!which) rampy[n * NP + slot] = make_float2(c * INV_N2, s * INV_N2);
  else        rampx[n * NP + slot] = make_float2(c, s);
}

// Precompute T = obja * exp(i*objp) over the full object volume.
__global__ void __launch_bounds__(256) init_T(const float* __restrict__ obja,
                                              const float* __restrict__ objp,
                                              float2* __restrict__ T) {
  int i = blockIdx.x * 256 + threadIdx.x;
  if (i >= OMODE * NZ * NYX * NYX) return;
  float a = obja[i], ph = objp[i];
  float s, c;
  __sincosf(ph, &s, &c);
  T[i] = make_float2(a * c, a * s);
}

// Sum the 8 (o,p) partials per batch element, applying omode occupancy here.
// part tile is TRANSPOSED: [blk][kx][ky].
__global__ void __launch_bounds__(256) reduce_dp(const float* __restrict__ part,
                                                 const float* __restrict__ occu,
                                                 float* __restrict__ dp) {
  int i = blockIdx.x * 256 + threadIdx.x;
  if (i >= BATCH * NP * NP) return;
  int n = i >> 14;
  int r = i & (NP * NP - 1);
  int ky = r >> 7, kx = r & (NP - 1);
  const float* b = part + ((size_t)n * 8 << 14) + (kx << 7) + ky;
  float w0 = occu[0], w1 = occu[1];
  float s = 0.f;
#pragma unroll
  for (int j = 0; j < 8; ++j) s = fmaf(b[(size_t)j << 14], (j < 4 ? w0 : w1), s);
  dp[i] = s;
}

__global__ void __launch_bounds__(1024) ptycho_chain(
    const float* __restrict__ obja, const float* __restrict__ objp,
    const float* __restrict__ probe, const float* __restrict__ shifts,
    const float* __restrict__ H, const float2* __restrict__ hpre,
    const float2* __restrict__ rampy, const float2* __restrict__ rampx,
    const float2* __restrict__ Tpre,
    const float* __restrict__ occu, const int* __restrict__ indices,
    const int* __restrict__ crop, float* __restrict__ dp,
    float* __restrict__ part, int mode_ws, int mode_T)
{
  extern __shared__ v2f fld[];             // [128][LSTR] interleaved re/im

  const int blk  = blockIdx.x;             // n*8 + o*4 + p
  const int n    = blk >> 3;
  const int o    = (blk >> 2) & 1;
  const int p    = blk & 3;
  const int tid  = threadIdx.x;
  const int wid  = tid >> 6;               // 16 waves
  const int lane = tid & 63;
  const int bp32 = (lane ^ 32) << 2;       // ds_bpermute byte index for xor-32

  const int   pos = indices[n];
  const int   cy  = crop[2 * pos + 0];
  const int   cx  = crop[2 * pos + 1];
  const float wocc = occu[o];

  // ---- twiddles ----------------------------------------------------------
  Tw tw;
  tw.g[0] = ((lane >> 0) & 1) ? -1.f : 1.f;
#pragma unroll
  for (int s = 1; s < 6; ++s) {
    int h = 1 << s;
    int j = lane & (h - 1);
    float ang = 3.14159265358979f * (float)j / (float)h;
    float ts_, tc_;
    __sincosf(ang, &ts_, &tc_);
    bool up = (lane >> s) & 1;
    tw.g[s]   = up ? -1.f : 1.f;
    tw.dwr[s] = up ? tc_ : 1.f;
    tw.dwi[s] = up ? -ts_ : 0.f;
  }
  __sincosf(3.14159265358979f * (float)lane * (1.f / 64.f), &tw.ts6, &tw.tc6);

  // ---- P0: load probe rows + forward row FFT ----------------------------
  const v2f* probe2 = (const v2f*)probe;
#pragma unroll 1
  for (int k0 = 0; k0 < 8; k0 += 2) {
    int r0 = wid * 8 + k0;
    v2f A0 = probe2[(p * NP + r0) * NP + lane];
    v2f B0 = probe2[(p * NP + r0) * NP + lane + 64];
    v2f A1 = probe2[(p * NP + r0 + 1) * NP + lane];
    v2f B1 = probe2[(p * NP + r0 + 1) * NP + lane + 64];
    dif128(A0, B0, tw, bp32); dif128(A1, B1, tw, bp32);
    fld[r0 * LSTR + lane]            = A0; fld[r0 * LSTR + lane + 64]       = B0;
    fld[(r0 + 1) * LSTR + lane]      = A1; fld[(r0 + 1) * LSTR + lane + 64] = B1;
  }
  __syncthreads();

  // fallback-only multiplies (no workspace)
  auto ramp_mul_fb = [&](v2f& A, v2f& B, int c) {
    float sh0v = shifts[2 * pos], sh1v = shifts[2 * pos + 1];
    int kxc = br7(c);
    float fx = (float)(kxc < 64 ? kxc : kxc - 128) * (1.f / 128.f);
    int ky0 = br7(lane);
    float fy0 = (float)(ky0 < 64 ? ky0 : ky0 - 128) * (1.f / 128.f);
    int ky1 = ky0 + 1;
    float fy1 = (float)(ky1 < 64 ? ky1 : ky1 - 128) * (1.f / 128.f);
    float com = fx * sh1v;
    float s0, c0_, s1, c1_;
    __sincosf(-6.28318530717959f * (fy0 * sh0v + com), &s0, &c0_);
    __sincosf(-6.28318530717959f * (fy1 * sh0v + com), &s1, &c1_);
    A = cmulv(A, c0_ * INV_N2, s0 * INV_N2);
    B = cmulv(B, c1_ * INV_N2, s1 * INV_N2);
  };
  auto h_mul_fb = [&](v2f& A, v2f& B, int c) {
    int kx = br7(c), ky0 = br7(lane);
    float hr0 = H[(ky0 * NP + kx) * 2], hi0 = H[(ky0 * NP + kx) * 2 + 1];
    float hr1 = H[((ky0 + 1) * NP + kx) * 2], hi1 = H[((ky0 + 1) * NP + kx) * 2 + 1];
    A = cmulv(A, hr0 * INV_N2, hi0 * INV_N2);
    B = cmulv(B, hr1 * INV_N2, hi1 * INV_N2);
  };

  // ---- column phase: Fcol, freq multiply, invCol ------------------------
  auto cphase = [&](int mode) {
    v2f ry0, ry1;
    if (mode == 0 && mode_ws) {
      float2 t0 = rampy[n * NP + lane];
      float2 t1 = rampy[n * NP + lane + 64];
      ry0 = (v2f){t0.x, t0.y}; ry1 = (v2f){t1.x, t1.y};
    }
#pragma unroll 1
    for (int k0 = 0; k0 < 8; k0 += 2) {
      int c0 = wid * 8 + k0, c1 = c0 + 1;
      float2 h00, h01, h10, h11;
      if (mode == 1 && mode_ws) {
        h00 = hpre[c0 * NP + lane]; h01 = hpre[c0 * NP + lane + 64];
        h10 = hpre[c1 * NP + lane]; h11 = hpre[c1 * NP + lane + 64];
      }
      float2 rx0, rx1;
      if (mode == 0 && mode_ws) {
        rx0 = rampx[n * NP + c0]; rx1 = rampx[n * NP + c1];
      }
      v2f A0 = fld[lane * LSTR + c0], B0 = fld[(lane + 64) * LSTR + c0];
      v2f A1 = fld[lane * LSTR + c1], B1 = fld[(lane + 64) * LSTR + c1];
      dif128(A0, B0, tw, bp32); dif128(A1, B1, tw, bp32);
      if (mode == 0) {
        if (mode_ws) {
          v2f m;
          m = cmulv(ry0, rx0.x, rx0.y); A0 = cmulvv(A0, m);
          m = cmulv(ry1, rx0.x, rx0.y); B0 = cmulvv(B0, m);
          m = cmulv(ry0, rx1.x, rx1.y); A1 = cmulvv(A1, m);
          m = cmulv(ry1, rx1.x, rx1.y); B1 = cmulvv(B1, m);
        } else {
          ramp_mul_fb(A0, B0, c0);
          ramp_mul_fb(A1, B1, c1);
        }
      } else {
        if (mode_ws) {
          A0 = cmulv(A0, h00.x, h00.y); B0 = cmulv(B0, h01.x, h01.y);
          A1 = cmulv(A1, h10.x, h10.y); B1 = cmulv(B1, h11.x, h11.y);
        } else {
          h_mul_fb(A0, B0, c0);
          h_mul_fb(A1, B1, c1);
        }
      }
      dit128(A0, B0, tw, bp32); dit128(A1, B1, tw, bp32);
      fld[lane * LSTR + c0]        = A0; fld[(lane + 64) * LSTR + c0] = B0;
      fld[lane * LSTR + c1]        = A1; fld[(lane + 64) * LSTR + c1] = B1;
    }
    __syncthreads();
  };

  // ---- row phase: invRow, multiply T(z), Frow ---------------------------
  auto rphase = [&](int z) {
#pragma unroll 1
    for (int k0 = 0; k0 < 8; k0 += 2) {
      int r0 = wid * 8 + k0;
      size_t ob0 = ((size_t)(o * NZ + z) * NYX + (size_t)(cy + r0)) * NYX + cx;
      size_t ob1 = ob0 + NYX;
      v2f A0 = fld[r0 * LSTR + lane],       B0 = fld[r0 * LSTR + lane + 64];
      v2f A1 = fld[(r0 + 1) * LSTR + lane], B1 = fld[(r0 + 1) * LSTR + lane + 64];
      if (mode_T) {
        float2 t00 = Tpre[ob0 + lane], t01 = Tpre[ob0 + lane + 64];
        float2 t10 = Tpre[ob1 + lane], t11 = Tpre[ob1 + lane + 64];
        dit128(A0, B0, tw, bp32); dit128(A1, B1, tw, bp32);
        A0 = cmulv(A0, t00.x, t00.y); B0 = cmulv(B0, t01.x, t01.y);
        A1 = cmulv(A1, t10.x, t10.y); B1 = cmulv(B1, t11.x, t11.y);
      } else {
        float pa00 = obja[ob0 + lane],      ph00 = objp[ob0 + lane];
        float pa01 = obja[ob0 + lane + 64], ph01 = objp[ob0 + lane + 64];
        float pa10 = obja[ob1 + lane],      ph10 = objp[ob1 + lane];
        float pa11 = obja[ob1 + lane + 64], ph11 = objp[ob1 + lane + 64];
        dit128(A0, B0, tw, bp32); dit128(A1, B1, tw, bp32);
        float s, c;
        __sincosf(ph00, &s, &c); A0 = cmulv(A0, pa00 * c, pa00 * s);
        __sincosf(ph01, &s, &c); B0 = cmulv(B0, pa01 * c, pa01 * s);
        __sincosf(ph10, &s, &c); A1 = cmulv(A1, pa10 * c, pa10 * s);
        __sincosf(ph11, &s, &c); B1 = cmulv(B1, pa11 * c, pa11 * s);
      }
      dif128(A0, B0, tw, bp32); dif128(A1, B1, tw, bp32);
      fld[r0 * LSTR + lane]            = A0; fld[r0 * LSTR + lane + 64]       = B0;
      fld[(r0 + 1) * LSTR + lane]      = A1; fld[(r0 + 1) * LSTR + lane + 64] = B1;
    }
    __syncthreads();
  };

  cphase(0);        // Fcol + ramp + invCol  (completes probe shift)
  rphase(0);        // invRow + T0 + Frow
#pragma unroll 1
  for (int z = 1; z < NZ; ++z) {
    cphase(1);      // Fcol + H + invCol     (propagation z-1 -> z)
    rphase(z);      // invRow + Tz + Frow
  }

  // ---- final column FFT -> |.|^2 -> store (transposed part tile) --------
#pragma unroll 1
  for (int k0 = 0; k0 < 8; k0 += 2) {
    int c0 = wid * 8 + k0, c1 = c0 + 1;
    v2f A0 = fld[lane * LSTR + c0], B0 = fld[(lane + 64) * LSTR + c0];
    v2f A1 = fld[lane * LSTR + c1], B1 = fld[(lane + 64) * LSTR + c1];
    dif128(A0, B0, tw, bp32); dif128(A1, B1, tw, bp32);
    int ky0 = br7(lane);
    float m00 = fmaf(A0.x, A0.x, A0.y * A0.y);
    float m01 = fmaf(B0.x, B0.x, B0.y * B0.y);
    float m10 = fmaf(A1.x, A1.x, A1.y * A1.y);
    float m11 = fmaf(B1.x, B1.x, B1.y * B1.y);
    if (mode_ws) {
      size_t b0 = ((size_t)blk << 14) + (size_t)br7(c0) * NP;
      size_t b1 = ((size_t)blk << 14) + (size_t)br7(c1) * NP;
      part[b0 + ky0]     = m00;     // occupancy weight applied in reduce_dp
      part[b0 + ky0 + 1] = m01;
      part[b1 + ky0]     = m10;
      part[b1 + ky0 + 1] = m11;
    } else {
      size_t base = ((size_t)n << 14);
      atomicAdd(&dp[base + (size_t)ky0 * NP + br7(c0)],       m00 * wocc);
      atomicAdd(&dp[base + (size_t)(ky0 + 1) * NP + br7(c0)], m01 * wocc);
      atomicAdd(&dp[base + (size_t)ky0 * NP + br7(c1)],       m10 * wocc);
      atomicAdd(&dp[base + (size_t)(ky0 + 1) * NP + br7(c1)], m11 * wocc);
    }
  }
}

extern "C" void kernel_launch(void* const* d_in, const int* in_sizes, int n_in,
                              void* d_out, int out_size, void* d_ws, size_t ws_size,
                              hipStream_t stream) {
  const float* obja   = (const float*)d_in[0];
  const float* objp   = (const float*)d_in[1];
  const float* probe  = (const float*)d_in[2];
  const float* shifts = (const float*)d_in[3];
  const float* H      = (const float*)d_in[4];
  const float* occu   = (const float*)d_in[5];
  const int*   indices = (const int*)d_in[6];
  const int*   crop    = (const int*)d_in[7];
  float* dp = (float*)d_out;

  const size_t part_bytes  = (size_t)BATCH * OMODE * PMODE * NP * NP * sizeof(float); // 32 MB
  const size_t hpre_bytes  = (size_t)NP * NP * sizeof(float2);                        // 128 KB
  const size_t ramp_bytes  = (size_t)BATCH * NP * sizeof(float2);                     // 64 KB each
  const size_t T_bytes     = (size_t)OMODE * NZ * NYX * NYX * sizeof(float2);         // 33.5 MB
  const size_t need_ws = part_bytes + hpre_bytes + 2 * ramp_bytes;
  const size_t need_T  = need_ws + T_bytes;

  int mode_ws = (ws_size >= need_ws) ? 1 : 0;
  int mode_T  = (ws_size >= need_T) ? 1 : 0;
  float*  part  = (float*)d_ws;
  float2* hpre  = (float2*)((char*)d_ws + part_bytes);
  float2* rampy = (float2*)((char*)d_ws + part_bytes + hpre_bytes);
  float2* rampx = (float2*)((char*)d_ws + part_bytes + hpre_bytes + ramp_bytes);
  float2* Tpre  = (float2*)((char*)d_ws + need_ws);

  if (mode_ws) {
    hipLaunchKernelGGL(init_hpre, dim3((NP * NP + 255) / 256), dim3(256), 0,
                       stream, H, hpre);
    hipLaunchKernelGGL(init_ramp, dim3((2 * BATCH * NP + 255) / 256), dim3(256), 0,
                       stream, shifts, indices, rampy, rampx);
  } else {
    // atomic fallback accumulates -> must zero output every call
    hipMemsetAsync(d_out, 0, (size_t)out_size * sizeof(float), stream);
  }
  if (mode_T) {
    hipLaunchKernelGGL(init_T, dim3((OMODE * NZ * NYX * NYX + 255) / 256), dim3(256),
                       0, stream, obja, objp, Tpre);
  }

  const int lds_bytes = NP * LSTR * (int)sizeof(float2);  // 132096
  hipFuncSetAttribute((const void*)ptycho_chain,
                      hipFuncAttributeMaxDynamicSharedMemorySize, lds_bytes);
  hipLaunchKernelGGL(ptycho_chain, dim3(BATCH * OMODE * PMODE), dim3(1024),
                     lds_bytes, stream,
                     obja, objp, probe, shifts, H, hpre, rampy, rampx, Tpre,
                     occu, indices, crop, dp, part, mode_ws, mode_T);
  if (mode_ws) {
    hipLaunchKernelGGL(reduce_dp, dim3((BATCH * NP * NP + 255) / 256), dim3(256),
                       0, stream, part, occu, dp);
  }
}

// Round 9
// 377.240 us; speedup vs baseline: 1.6129x; 1.0272x over previous
//
#include <hip/hip_runtime.h>

// ---- problem constants --------------------------------------------------
static constexpr int OMODE = 2, PMODE = 4, NZ = 8;
static constexpr int NYX = 512;   // object plane 512x512
static constexpr int NP  = 128;   // probe / tile 128x128
static constexpr int BATCH = 64;
static constexpr int LSTR = 129;  // padded LDS line stride (float2 units)
static constexpr float INV_N2 = 1.0f / 16384.0f;   // 1/(128*128) ifft2 norm

typedef float v2f __attribute__((ext_vector_type(2)));

__device__ __forceinline__ int br7(int x) { return (int)(__brev((unsigned)x) >> 25); }

__device__ __forceinline__ v2f splat2(float s) { return (v2f){s, s}; }
__device__ __forceinline__ v2f swapv(v2f v) { return __builtin_shufflevector(v, v, 1, 0); }
__device__ __forceinline__ v2f cmulv(v2f a, float br_, float bi_) {
  return a * splat2(br_) + swapv(a) * (v2f){-bi_, bi_};
}
__device__ __forceinline__ v2f cmulvv(v2f a, v2f b) {
  return a * splat2(b.x) + swapv(a) * (v2f){-b.y, b.y};
}

// ---- cross-lane exchange ------------------------------------------------
template<int CTRL>
__device__ __forceinline__ float dppf(float x) {
  int i = __float_as_int(x);
  int r = __builtin_amdgcn_update_dpp(i, i, CTRL, 0xF, 0xF, false);
  return __int_as_float(r);
}

// Per-thread twiddles, scalars only (compile-time indexed) -> VGPRs.
struct Tw {
  float tc6, ts6;            // cos/sin(pi*lane/64) for the register stage
  float g[6];                // +1 lower lane of pair, -1 upper
  float dwr[6], dwi[6];      // DIF post-mul: up ? conj(w) : 1   (DIT uses dwr,-dwi)
};

// butterfly d = partner + g*own, via DPP (H=1,2)
template<int CTRL, int S>
__device__ __forceinline__ v2f bfly_dpp(v2f m, const Tw& tw) {
  v2f t = (v2f){dppf<CTRL>(m.x), dppf<CTRL>(m.y)};
  return t + splat2(tw.g[S]) * m;
}
// butterfly via ds_swizzle (H=4,8,16): OFS = (H<<10)|0x1F
template<int OFS, int S>
__device__ __forceinline__ v2f bfly_swz(v2f m, const Tw& tw) {
  v2f t;
  t.x = __int_as_float(__builtin_amdgcn_ds_swizzle(__float_as_int(m.x), OFS));
  t.y = __int_as_float(__builtin_amdgcn_ds_swizzle(__float_as_int(m.y), OFS));
  return t + splat2(tw.g[S]) * m;
}
// butterfly via ds_bpermute (H=32): bp32 = (lane^32)<<2, full-wave64 permute
__device__ __forceinline__ v2f bfly_bp32(v2f m, int bp32, float g5) {
  v2f t;
  t.x = __int_as_float(__builtin_amdgcn_ds_bpermute(bp32, __float_as_int(m.x)));
  t.y = __int_as_float(__builtin_amdgcn_ds_bpermute(bp32, __float_as_int(m.y)));
  return t + splat2(g5) * m;
}

template<int S> __device__ __forceinline__ v2f twd(v2f d, const Tw& tw) {  // dif post-mul
  return d * splat2(tw.dwr[S]) + swapv(d) * (v2f){-tw.dwi[S], tw.dwi[S]};
}
template<int S> __device__ __forceinline__ v2f twc(v2f a, const Tw& tw) {  // dit pre-mul (conj)
  return a * splat2(tw.dwr[S]) + swapv(a) * (v2f){tw.dwi[S], -tw.dwi[S]};
}

// Forward 128-pt DIF: natural-order input -> bit-reversed-order slots.
__device__ __forceinline__ void dif128(v2f& A, v2f& B, const Tw& tw, int bp32) {
  { // register stage h=64: w = e^{-i*pi*lane/64}
    v2f d = A - B;
    A = A + B;
    B = d * splat2(tw.tc6) + swapv(d) * (v2f){tw.ts6, -tw.ts6};
  }
  A = twd<5>(bfly_bp32(A, bp32, tw.g[5]), tw);  B = twd<5>(bfly_bp32(B, bp32, tw.g[5]), tw);
  A = twd<4>(bfly_swz<0x401F, 4>(A, tw), tw);   B = twd<4>(bfly_swz<0x401F, 4>(B, tw), tw);
  A = twd<3>(bfly_swz<0x201F, 3>(A, tw), tw);   B = twd<3>(bfly_swz<0x201F, 3>(B, tw), tw);
  A = twd<2>(bfly_swz<0x101F, 2>(A, tw), tw);   B = twd<2>(bfly_swz<0x101F, 2>(B, tw), tw);
  A = twd<1>(bfly_dpp<0x4E, 1>(A, tw), tw);     B = twd<1>(bfly_dpp<0x4E, 1>(B, tw), tw);
  A = bfly_dpp<0xB1, 0>(A, tw);                 B = bfly_dpp<0xB1, 0>(B, tw);  // stage 0: w=1
}

// Inverse (unnormalized) 128-pt DIT: bit-reversed slots -> natural order.
__device__ __forceinline__ void dit128(v2f& A, v2f& B, const Tw& tw, int bp32) {
  A = bfly_dpp<0xB1, 0>(A, tw);                 B = bfly_dpp<0xB1, 0>(B, tw);  // stage 0: w=1
  A = bfly_dpp<0x4E, 1>(twc<1>(A, tw), tw);     B = bfly_dpp<0x4E, 1>(twc<1>(B, tw), tw);
  A = bfly_swz<0x101F, 2>(twc<2>(A, tw), tw);   B = bfly_swz<0x101F, 2>(twc<2>(B, tw), tw);
  A = bfly_swz<0x201F, 3>(twc<3>(A, tw), tw);   B = bfly_swz<0x201F, 3>(twc<3>(B, tw), tw);
  A = bfly_swz<0x401F, 4>(twc<4>(A, tw), tw);   B = bfly_swz<0x401F, 4>(twc<4>(B, tw), tw);
  A = bfly_bp32(twc<5>(A, tw), bp32, tw.g[5]);  B = bfly_bp32(twc<5>(B, tw), bp32, tw.g[5]);
  { // register stage h=64: w = e^{+i*pi*lane/64}
    v2f m = B * splat2(tw.tc6) + swapv(B) * (v2f){-tw.ts6, tw.ts6};
    B = A - m;
    A = A + m;
  }
}

// Pre-scramble H into workspace: hp[px][py] = H[br(py)][br(px)] * (1/N^2).
__global__ void __launch_bounds__(256) init_hpre(const float* __restrict__ H,
                                                 float2* __restrict__ hp) {
  int i = blockIdx.x * blockDim.x + threadIdx.x;
  if (i >= NP * NP) return;
  int px = i >> 7, py = i & (NP - 1);
  int ky = br7(py), kx = br7(px);
  hp[px * NP + py] = make_float2(H[(ky * NP + kx) * 2 + 0] * INV_N2,
                                 H[(ky * NP + kx) * 2 + 1] * INV_N2);
}

// Per-n shift ramps at bit-reversed slot positions.
__global__ void __launch_bounds__(256) init_ramp(const float* __restrict__ shifts,
                                                 const int* __restrict__ indices,
                                                 float2* __restrict__ rampy,
                                                 float2* __restrict__ rampx) {
  int i = blockIdx.x * blockDim.x + threadIdx.x;
  if (i >= 2 * BATCH * NP) return;
  int which = (i >= BATCH * NP) ? 1 : 0;
  int r = i - which * BATCH * NP;
  int n = r >> 7, slot = r & (NP - 1);
  int pos = indices[n];
  float sh = shifts[2 * pos + which];
  int k = br7(slot);
  float f = (float)(k < 64 ? k : k - 128) * (1.f / 128.f);
  float s, c;
  __sincosf(-6.28318530717959f * f * sh, &s, &c);
  if (!which) rampy[n * NP + slot] = make_float2(c * INV_N2, s * INV_N2);
  else        rampx[n * NP + slot] = make_float2(c, s);
}

// Precompute T = obja * exp(i*objp) over the full object volume.
__global__ void __launch_bounds__(256) init_T(const float* __restrict__ obja,
                                              const float* __restrict__ objp,
                                              float2* __restrict__ T) {
  int i = blockIdx.x * 256 + threadIdx.x;
  if (i >= OMODE * NZ * NYX * NYX) return;
  float a = obja[i], ph = objp[i];
  float s, c;
  __sincosf(ph, &s, &c);
  T[i] = make_float2(a * c, a * s);
}

// Sum the 8 (o,p) partials per batch element, applying omode occupancy here.
// part tile is TRANSPOSED: [blk][kx][ky].
__global__ void __launch_bounds__(256) reduce_dp(const float* __restrict__ part,
                                                 const float* __restrict__ occu,
                                                 float* __restrict__ dp) {
  int i = blockIdx.x * 256 + threadIdx.x;
  if (i >= BATCH * NP * NP) return;
  int n = i >> 14;
  int r = i & (NP * NP - 1);
  int ky = r >> 7, kx = r & (NP - 1);
  const float* b = part + ((size_t)n * 8 << 14) + (kx << 7) + ky;
  float w0 = occu[0], w1 = occu[1];
  float s = 0.f;
#pragma unroll
  for (int j = 0; j < 8; ++j) s = fmaf(b[(size_t)j << 14], (j < 4 ? w0 : w1), s);
  dp[i] = s;
}

__global__ void __launch_bounds__(1024, 2) ptycho_chain(
    const float* __restrict__ obja, const float* __restrict__ objp,
    const float* __restrict__ probe, const float* __restrict__ shifts,
    const float* __restrict__ H, const float2* __restrict__ hpre,
    const float2* __restrict__ rampy, const float2* __restrict__ rampx,
    const float2* __restrict__ Tpre,
    const float* __restrict__ occu, const int* __restrict__ indices,
    const int* __restrict__ crop, float* __restrict__ dp,
    float* __restrict__ part, int mode_ws, int mode_T)
{
  extern __shared__ v2f fld[];             // [128][LSTR] interleaved re/im

  const int blk  = blockIdx.x;             // n*8 + o*4 + p
  const int n    = blk >> 3;
  const int o    = (blk >> 2) & 1;
  const int p    = blk & 3;
  const int tid  = threadIdx.x;
  const int wid  = tid >> 6;               // 16 waves
  const int lane = tid & 63;
  const int bp32 = (lane ^ 32) << 2;       // ds_bpermute byte index for xor-32

  const int   pos = indices[n];
  const int   cy  = crop[2 * pos + 0];
  const int   cx  = crop[2 * pos + 1];
  const float wocc = occu[o];

  // ---- twiddles ----------------------------------------------------------
  Tw tw;
  tw.g[0] = ((lane >> 0) & 1) ? -1.f : 1.f;
#pragma unroll
  for (int s = 1; s < 6; ++s) {
    int h = 1 << s;
    int j = lane & (h - 1);
    float ang = 3.14159265358979f * (float)j / (float)h;
    float ts_, tc_;
    __sincosf(ang, &ts_, &tc_);
    bool up = (lane >> s) & 1;
    tw.g[s]   = up ? -1.f : 1.f;
    tw.dwr[s] = up ? tc_ : 1.f;
    tw.dwi[s] = up ? -ts_ : 0.f;
  }
  __sincosf(3.14159265358979f * (float)lane * (1.f / 64.f), &tw.ts6, &tw.tc6);

  // ---- P0: load probe rows + forward row FFT (ILP-4) --------------------
  const v2f* probe2 = (const v2f*)probe;
#pragma unroll 1
  for (int k0 = 0; k0 < 8; k0 += 4) {
    int r0 = wid * 8 + k0;
    v2f A[4], B[4];
#pragma unroll
    for (int kk = 0; kk < 4; ++kk) {
      A[kk] = probe2[(p * NP + r0 + kk) * NP + lane];
      B[kk] = probe2[(p * NP + r0 + kk) * NP + lane + 64];
    }
#pragma unroll
    for (int kk = 0; kk < 4; ++kk) dif128(A[kk], B[kk], tw, bp32);
#pragma unroll
    for (int kk = 0; kk < 4; ++kk) {
      fld[(r0 + kk) * LSTR + lane]      = A[kk];
      fld[(r0 + kk) * LSTR + lane + 64] = B[kk];
    }
  }
  __syncthreads();

  // fallback-only multiplies (no workspace)
  auto ramp_mul_fb = [&](v2f& A, v2f& B, int c) {
    float sh0v = shifts[2 * pos], sh1v = shifts[2 * pos + 1];
    int kxc = br7(c);
    float fx = (float)(kxc < 64 ? kxc : kxc - 128) * (1.f / 128.f);
    int ky0 = br7(lane);
    float fy0 = (float)(ky0 < 64 ? ky0 : ky0 - 128) * (1.f / 128.f);
    int ky1 = ky0 + 1;
    float fy1 = (float)(ky1 < 64 ? ky1 : ky1 - 128) * (1.f / 128.f);
    float com = fx * sh1v;
    float s0, c0_, s1, c1_;
    __sincosf(-6.28318530717959f * (fy0 * sh0v + com), &s0, &c0_);
    __sincosf(-6.28318530717959f * (fy1 * sh0v + com), &s1, &c1_);
    A = cmulv(A, c0_ * INV_N2, s0 * INV_N2);
    B = cmulv(B, c1_ * INV_N2, s1 * INV_N2);
  };
  auto h_mul_fb = [&](v2f& A, v2f& B, int c) {
    int kx = br7(c), ky0 = br7(lane);
    float hr0 = H[(ky0 * NP + kx) * 2], hi0 = H[(ky0 * NP + kx) * 2 + 1];
    float hr1 = H[((ky0 + 1) * NP + kx) * 2], hi1 = H[((ky0 + 1) * NP + kx) * 2 + 1];
    A = cmulv(A, hr0 * INV_N2, hi0 * INV_N2);
    B = cmulv(B, hr1 * INV_N2, hi1 * INV_N2);
  };

  // ---- column phase: Fcol, freq multiply, invCol (ILP-4) ----------------
  auto cphase = [&](int mode) {
    v2f ry0, ry1;
    if (mode == 0 && mode_ws) {
      float2 t0 = rampy[n * NP + lane];
      float2 t1 = rampy[n * NP + lane + 64];
      ry0 = (v2f){t0.x, t0.y}; ry1 = (v2f){t1.x, t1.y};
    }
#pragma unroll 1
    for (int k0 = 0; k0 < 8; k0 += 4) {
      int c0 = wid * 8 + k0;
      float2 h0[4], h1[4], rx[4];
      if (mode == 1 && mode_ws) {
#pragma unroll
        for (int kk = 0; kk < 4; ++kk) {
          h0[kk] = hpre[(c0 + kk) * NP + lane];
          h1[kk] = hpre[(c0 + kk) * NP + lane + 64];
        }
      }
      if (mode == 0 && mode_ws) {
#pragma unroll
        for (int kk = 0; kk < 4; ++kk) rx[kk] = rampx[n * NP + c0 + kk];
      }
      v2f A[4], B[4];
#pragma unroll
      for (int kk = 0; kk < 4; ++kk) {
        A[kk] = fld[lane * LSTR + c0 + kk];
        B[kk] = fld[(lane + 64) * LSTR + c0 + kk];
      }
#pragma unroll
      for (int kk = 0; kk < 4; ++kk) dif128(A[kk], B[kk], tw, bp32);
      if (mode == 0) {
        if (mode_ws) {
#pragma unroll
          for (int kk = 0; kk < 4; ++kk) {
            v2f m;
            m = cmulv(ry0, rx[kk].x, rx[kk].y); A[kk] = cmulvv(A[kk], m);
            m = cmulv(ry1, rx[kk].x, rx[kk].y); B[kk] = cmulvv(B[kk], m);
          }
        } else {
#pragma unroll
          for (int kk = 0; kk < 4; ++kk) ramp_mul_fb(A[kk], B[kk], c0 + kk);
        }
      } else {
        if (mode_ws) {
#pragma unroll
          for (int kk = 0; kk < 4; ++kk) {
            A[kk] = cmulv(A[kk], h0[kk].x, h0[kk].y);
            B[kk] = cmulv(B[kk], h1[kk].x, h1[kk].y);
          }
        } else {
#pragma unroll
          for (int kk = 0; kk < 4; ++kk) h_mul_fb(A[kk], B[kk], c0 + kk);
        }
      }
#pragma unroll
      for (int kk = 0; kk < 4; ++kk) dit128(A[kk], B[kk], tw, bp32);
#pragma unroll
      for (int kk = 0; kk < 4; ++kk) {
        fld[lane * LSTR + c0 + kk]        = A[kk];
        fld[(lane + 64) * LSTR + c0 + kk] = B[kk];
      }
    }
    __syncthreads();
  };

  // ---- row phase: invRow, multiply T(z), Frow (ILP-4) -------------------
  auto rphase = [&](int z) {
#pragma unroll 1
    for (int k0 = 0; k0 < 8; k0 += 4) {
      int r0 = wid * 8 + k0;
      size_t ob = ((size_t)(o * NZ + z) * NYX + (size_t)(cy + r0)) * NYX + cx;
      v2f A[4], B[4];
#pragma unroll
      for (int kk = 0; kk < 4; ++kk) {
        A[kk] = fld[(r0 + kk) * LSTR + lane];
        B[kk] = fld[(r0 + kk) * LSTR + lane + 64];
      }
      if (mode_T) {
        float2 t0[4], t1[4];
#pragma unroll
        for (int kk = 0; kk < 4; ++kk) {
          t0[kk] = Tpre[ob + (size_t)kk * NYX + lane];
          t1[kk] = Tpre[ob + (size_t)kk * NYX + lane + 64];
        }
#pragma unroll
        for (int kk = 0; kk < 4; ++kk) dit128(A[kk], B[kk], tw, bp32);
#pragma unroll
        for (int kk = 0; kk < 4; ++kk) {
          A[kk] = cmulv(A[kk], t0[kk].x, t0[kk].y);
          B[kk] = cmulv(B[kk], t1[kk].x, t1[kk].y);
        }
      } else {
        float pa0[4], ph0[4], pa1[4], ph1[4];
#pragma unroll
        for (int kk = 0; kk < 4; ++kk) {
          pa0[kk] = obja[ob + (size_t)kk * NYX + lane];
          ph0[kk] = objp[ob + (size_t)kk * NYX + lane];
          pa1[kk] = obja[ob + (size_t)kk * NYX + lane + 64];
          ph1[kk] = objp[ob + (size_t)kk * NYX + lane + 64];
        }
#pragma unroll
        for (int kk = 0; kk < 4; ++kk) dit128(A[kk], B[kk], tw, bp32);
#pragma unroll
        for (int kk = 0; kk < 4; ++kk) {
          float s, c;
          __sincosf(ph0[kk], &s, &c); A[kk] = cmulv(A[kk], pa0[kk] * c, pa0[kk] * s);
          __sincosf(ph1[kk], &s, &c); B[kk] = cmulv(B[kk], pa1[kk] * c, pa1[kk] * s);
        }
      }
#pragma unroll
      for (int kk = 0; kk < 4; ++kk) dif128(A[kk], B[kk], tw, bp32);
#pragma unroll
      for (int kk = 0; kk < 4; ++kk) {
        fld[(r0 + kk) * LSTR + lane]      = A[kk];
        fld[(r0 + kk) * LSTR + lane + 64] = B[kk];
      }
    }
    __syncthreads();
  };

  cphase(0);        // Fcol + ramp + invCol  (completes probe shift)
  rphase(0);        // invRow + T0 + Frow
#pragma unroll 1
  for (int z = 1; z < NZ; ++z) {
    cphase(1);      // Fcol + H + invCol     (propagation z-1 -> z)
    rphase(z);      // invRow + Tz + Frow
  }

  // ---- final column FFT -> |.|^2 -> store (transposed part tile) --------
#pragma unroll 1
  for (int k0 = 0; k0 < 8; k0 += 4) {
    int c0 = wid * 8 + k0;
    v2f A[4], B[4];
#pragma unroll
    for (int kk = 0; kk < 4; ++kk) {
      A[kk] = fld[lane * LSTR + c0 + kk];
      B[kk] = fld[(lane + 64) * LSTR + c0 + kk];
    }
#pragma unroll
    for (int kk = 0; kk < 4; ++kk) dif128(A[kk], B[kk], tw, bp32);
    int ky0 = br7(lane);
#pragma unroll
    for (int kk = 0; kk < 4; ++kk) {
      float m0 = fmaf(A[kk].x, A[kk].x, A[kk].y * A[kk].y);
      float m1 = fmaf(B[kk].x, B[kk].x, B[kk].y * B[kk].y);
      if (mode_ws) {
        size_t b0 = ((size_t)blk << 14) + (size_t)br7(c0 + kk) * NP;
        part[b0 + ky0]     = m0;    // occupancy weight applied in reduce_dp
        part[b0 + ky0 + 1] = m1;
      } else {
        size_t base = ((size_t)n << 14);
        atomicAdd(&dp[base + (size_t)ky0 * NP + br7(c0 + kk)],       m0 * wocc);
        atomicAdd(&dp[base + (size_t)(ky0 + 1) * NP + br7(c0 + kk)], m1 * wocc);
      }
    }
  }
}

extern "C" void kernel_launch(void* const* d_in, const int* in_sizes, int n_in,
                              void* d_out, int out_size, void* d_ws, size_t ws_size,
                              hipStream_t stream) {
  const float* obja   = (const float*)d_in[0];
  const float* objp   = (const float*)d_in[1];
  const float* probe  = (const float*)d_in[2];
  const float* shifts = (const float*)d_in[3];
  const float* H      = (const float*)d_in[4];
  const float* occu   = (const float*)d_in[5];
  const int*   indices = (const int*)d_in[6];
  const int*   crop    = (const int*)d_in[7];
  float* dp = (float*)d_out;

  const size_t part_bytes  = (size_t)BATCH * OMODE * PMODE * NP * NP * sizeof(float); // 32 MB
  const size_t hpre_bytes  = (size_t)NP * NP * sizeof(float2);                        // 128 KB
  const size_t ramp_bytes  = (size_t)BATCH * NP * sizeof(float2);                     // 64 KB each
  const size_t T_bytes     = (size_t)OMODE * NZ * NYX * NYX * sizeof(float2);         // 33.5 MB
  const size_t need_ws = part_bytes + hpre_bytes + 2 * ramp_bytes;
  const size_t need_T  = need_ws + T_bytes;

  int mode_ws = (ws_size >= need_ws) ? 1 : 0;
  int mode_T  = (ws_size >= need_T) ? 1 : 0;
  float*  part  = (float*)d_ws;
  float2* hpre  = (float2*)((char*)d_ws + part_bytes);
  float2* rampy = (float2*)((char*)d_ws + part_bytes + hpre_bytes);
  float2* rampx = (float2*)((char*)d_ws + part_bytes + hpre_bytes + ramp_bytes);
  float2* Tpre  = (float2*)((char*)d_ws + need_ws);

  if (mode_ws) {
    hipLaunchKernelGGL(init_hpre, dim3((NP * NP + 255) / 256), dim3(256), 0,
                       stream, H, hpre);
    hipLaunchKernelGGL(init_ramp, dim3((2 * BATCH * NP + 255) / 256), dim3(256), 0,
                       stream, shifts, indices, rampy, rampx);
  } else {
    // atomic fallback accumulates -> must zero output every call
    hipMemsetAsync(d_out, 0, (size_t)out_size * sizeof(float), stream);
  }
  if (mode_T) {
    hipLaunchKernelGGL(init_T, dim3((OMODE * NZ * NYX * NYX + 255) / 256), dim3(256),
                       0, stream, obja, objp, Tpre);
  }

  const int lds_bytes = NP * LSTR * (int)sizeof(float2);  // 132096
  hipFuncSetAttribute((const void*)ptycho_chain,
                      hipFuncAttributeMaxDynamicSharedMemorySize, lds_bytes);
  hipLaunchKernelGGL(ptycho_chain, dim3(BATCH * OMODE * PMODE), dim3(1024),
                     lds_bytes, stream,
                     obja, objp, probe, shifts, H, hpre, rampy, rampx, Tpre,
                     occu, indices, crop, dp, part, mode_ws, mode_T);
  if (mode_ws) {
    hipLaunchKernelGGL(reduce_dp, dim3((BATCH * NP * NP + 255) / 256), dim3(256),
                       0, stream, part, occu, dp);
  }
}

// Round 10
// 376.118 us; speedup vs baseline: 1.6177x; 1.0030x over previous
//
#include <hip/hip_runtime.h>

// ---- problem constants --------------------------------------------------
static constexpr int OMODE = 2, PMODE = 4, NZ = 8;
static constexpr int NYX = 512;   // object plane 512x512
static constexpr int NP  = 128;   // probe / tile 128x128
static constexpr int BATCH = 64;
static constexpr int LSTR = 129;  // padded LDS line stride (float2 units)
static constexpr float INV_N2 = 1.0f / 16384.0f;   // 1/(128*128) ifft2 norm

typedef float v2f __attribute__((ext_vector_type(2)));

__device__ __forceinline__ int br7(int x) { return (int)(__brev((unsigned)x) >> 25); }

__device__ __forceinline__ v2f splat2(float s) { return (v2f){s, s}; }
__device__ __forceinline__ v2f swapv(v2f v) { return __builtin_shufflevector(v, v, 1, 0); }
__device__ __forceinline__ v2f cmulv(v2f a, float br_, float bi_) {
  return a * splat2(br_) + swapv(a) * (v2f){-bi_, bi_};
}
__device__ __forceinline__ v2f cmulvv(v2f a, v2f b) {
  return a * splat2(b.x) + swapv(a) * (v2f){-b.y, b.y};
}

// ---- cross-lane exchange ------------------------------------------------
template<int CTRL>
__device__ __forceinline__ float dppf(float x) {
  int i = __float_as_int(x);
  int r = __builtin_amdgcn_update_dpp(i, i, CTRL, 0xF, 0xF, false);
  return __int_as_float(r);
}

// Per-thread twiddles, scalars only (compile-time indexed) -> VGPRs.
struct Tw {
  float tc6, ts6;            // cos/sin(pi*lane/64) for the register stage
  float g[6];                // +1 lower lane of pair, -1 upper
  float dwr[6], dwi[6];      // DIF post-mul: up ? conj(w) : 1   (DIT uses dwr,-dwi)
};

// butterfly d = partner + g*own, via DPP (H=1,2)
template<int CTRL, int S>
__device__ __forceinline__ v2f bfly_dpp(v2f m, const Tw& tw) {
  v2f t = (v2f){dppf<CTRL>(m.x), dppf<CTRL>(m.y)};
  return t + splat2(tw.g[S]) * m;
}
// butterfly via ds_swizzle (H=4,8,16): OFS = (H<<10)|0x1F
template<int OFS, int S>
__device__ __forceinline__ v2f bfly_swz(v2f m, const Tw& tw) {
  v2f t;
  t.x = __int_as_float(__builtin_amdgcn_ds_swizzle(__float_as_int(m.x), OFS));
  t.y = __int_as_float(__builtin_amdgcn_ds_swizzle(__float_as_int(m.y), OFS));
  return t + splat2(tw.g[S]) * m;
}
// butterfly via ds_bpermute (H=32): bp32 = (lane^32)<<2, full-wave64 permute
__device__ __forceinline__ v2f bfly_bp32(v2f m, int bp32, float g5) {
  v2f t;
  t.x = __int_as_float(__builtin_amdgcn_ds_bpermute(bp32, __float_as_int(m.x)));
  t.y = __int_as_float(__builtin_amdgcn_ds_bpermute(bp32, __float_as_int(m.y)));
  return t + splat2(g5) * m;
}

template<int S> __device__ __forceinline__ v2f twd(v2f d, const Tw& tw) {  // dif post-mul
  return d * splat2(tw.dwr[S]) + swapv(d) * (v2f){-tw.dwi[S], tw.dwi[S]};
}
template<int S> __device__ __forceinline__ v2f twc(v2f a, const Tw& tw) {  // dit pre-mul (conj)
  return a * splat2(tw.dwr[S]) + swapv(a) * (v2f){tw.dwi[S], -tw.dwi[S]};
}

// Forward 128-pt DIF: natural-order input -> bit-reversed-order slots.
__device__ __forceinline__ void dif128(v2f& A, v2f& B, const Tw& tw, int bp32) {
  { // register stage h=64: w = e^{-i*pi*lane/64}
    v2f d = A - B;
    A = A + B;
    B = d * splat2(tw.tc6) + swapv(d) * (v2f){tw.ts6, -tw.ts6};
  }
  A = twd<5>(bfly_bp32(A, bp32, tw.g[5]), tw);  B = twd<5>(bfly_bp32(B, bp32, tw.g[5]), tw);
  A = twd<4>(bfly_swz<0x401F, 4>(A, tw), tw);   B = twd<4>(bfly_swz<0x401F, 4>(B, tw), tw);
  A = twd<3>(bfly_swz<0x201F, 3>(A, tw), tw);   B = twd<3>(bfly_swz<0x201F, 3>(B, tw), tw);
  A = twd<2>(bfly_swz<0x101F, 2>(A, tw), tw);   B = twd<2>(bfly_swz<0x101F, 2>(B, tw), tw);
  A = twd<1>(bfly_dpp<0x4E, 1>(A, tw), tw);     B = twd<1>(bfly_dpp<0x4E, 1>(B, tw), tw);
  A = bfly_dpp<0xB1, 0>(A, tw);                 B = bfly_dpp<0xB1, 0>(B, tw);  // stage 0: w=1
}

// Inverse (unnormalized) 128-pt DIT: bit-reversed slots -> natural order.
__device__ __forceinline__ void dit128(v2f& A, v2f& B, const Tw& tw, int bp32) {
  A = bfly_dpp<0xB1, 0>(A, tw);                 B = bfly_dpp<0xB1, 0>(B, tw);  // stage 0: w=1
  A = bfly_dpp<0x4E, 1>(twc<1>(A, tw), tw);     B = bfly_dpp<0x4E, 1>(twc<1>(B, tw), tw);
  A = bfly_swz<0x101F, 2>(twc<2>(A, tw), tw);   B = bfly_swz<0x101F, 2>(twc<2>(B, tw), tw);
  A = bfly_swz<0x201F, 3>(twc<3>(A, tw), tw);   B = bfly_swz<0x201F, 3>(twc<3>(B, tw), tw);
  A = bfly_swz<0x401F, 4>(twc<4>(A, tw), tw);   B = bfly_swz<0x401F, 4>(twc<4>(B, tw), tw);
  A = bfly_bp32(twc<5>(A, tw), bp32, tw.g[5]);  B = bfly_bp32(twc<5>(B, tw), bp32, tw.g[5]);
  { // register stage h=64: w = e^{+i*pi*lane/64}
    v2f m = B * splat2(tw.tc6) + swapv(B) * (v2f){-tw.ts6, tw.ts6};
    B = A - m;
    A = A + m;
  }
}

// Pre-scramble H into workspace: hp[px][py] = H[br(py)][br(px)] * (1/N^2).
__global__ void __launch_bounds__(256) init_hpre(const float* __restrict__ H,
                                                 float2* __restrict__ hp) {
  int i = blockIdx.x * blockDim.x + threadIdx.x;
  if (i >= NP * NP) return;
  int px = i >> 7, py = i & (NP - 1);
  int ky = br7(py), kx = br7(px);
  hp[px * NP + py] = make_float2(H[(ky * NP + kx) * 2 + 0] * INV_N2,
                                 H[(ky * NP + kx) * 2 + 1] * INV_N2);
}

// Per-n shift ramps at bit-reversed slot positions.
__global__ void __launch_bounds__(256) init_ramp(const float* __restrict__ shifts,
                                                 const int* __restrict__ indices,
                                                 float2* __restrict__ rampy,
                                                 float2* __restrict__ rampx) {
  int i = blockIdx.x * blockDim.x + threadIdx.x;
  if (i >= 2 * BATCH * NP) return;
  int which = (i >= BATCH * NP) ? 1 : 0;
  int r = i - which * BATCH * NP;
  int n = r >> 7, slot = r & (NP - 1);
  int pos = indices[n];
  float sh = shifts[2 * pos + which];
  int k = br7(slot);
  float f = (float)(k < 64 ? k : k - 128) * (1.f / 128.f);
  float s, c;
  __sincosf(-6.28318530717959f * f * sh, &s, &c);
  if (!which) rampy[n * NP + slot] = make_float2(c * INV_N2, s * INV_N2);
  else        rampx[n * NP + slot] = make_float2(c, s);
}

// Precompute T = obja * exp(i*objp) over the full object volume.
__global__ void __launch_bounds__(256) init_T(const float* __restrict__ obja,
                                              const float* __restrict__ objp,
                                              float2* __restrict__ T) {
  int i = blockIdx.x * 256 + threadIdx.x;
  if (i >= OMODE * NZ * NYX * NYX) return;
  float a = obja[i], ph = objp[i];
  float s, c;
  __sincosf(ph, &s, &c);
  T[i] = make_float2(a * c, a * s);
}

// Sum the 8 (o,p) partials per batch element, applying omode occupancy here.
// part tile is TRANSPOSED: [blk][kx][ky].
__global__ void __launch_bounds__(256) reduce_dp(const float* __restrict__ part,
                                                 const float* __restrict__ occu,
                                                 float* __restrict__ dp) {
  int i = blockIdx.x * 256 + threadIdx.x;
  if (i >= BATCH * NP * NP) return;
  int n = i >> 14;
  int r = i & (NP * NP - 1);
  int ky = r >> 7, kx = r & (NP - 1);
  const float* b = part + ((size_t)n * 8 << 14) + (kx << 7) + ky;
  float w0 = occu[0], w1 = occu[1];
  float s = 0.f;
#pragma unroll
  for (int j = 0; j < 8; ++j) s = fmaf(b[(size_t)j << 14], (j < 4 ? w0 : w1), s);
  dp[i] = s;
}

__global__ void
__attribute__((amdgpu_flat_work_group_size(1024, 1024), amdgpu_waves_per_eu(4, 4)))
ptycho_chain(
    const float* __restrict__ obja, const float* __restrict__ objp,
    const float* __restrict__ probe, const float* __restrict__ shifts,
    const float* __restrict__ H, const float2* __restrict__ hpre,
    const float2* __restrict__ rampy, const float2* __restrict__ rampx,
    const float2* __restrict__ Tpre,
    const float* __restrict__ occu, const int* __restrict__ indices,
    const int* __restrict__ crop, float* __restrict__ dp,
    float* __restrict__ part, int mode_ws, int mode_T)
{
  extern __shared__ v2f fld[];             // [128][LSTR] interleaved re/im

  const int blk  = blockIdx.x;             // n*8 + o*4 + p
  const int n    = blk >> 3;
  const int o    = (blk >> 2) & 1;
  const int p    = blk & 3;
  const int tid  = threadIdx.x;
  const int wid  = tid >> 6;               // 16 waves
  const int lane = tid & 63;
  const int bp32 = (lane ^ 32) << 2;       // ds_bpermute byte index for xor-32

  const int   pos = indices[n];
  const int   cy  = crop[2 * pos + 0];
  const int   cx  = crop[2 * pos + 1];
  const float wocc = occu[o];

  // ---- twiddles ----------------------------------------------------------
  Tw tw;
  tw.g[0] = ((lane >> 0) & 1) ? -1.f : 1.f;
#pragma unroll
  for (int s = 1; s < 6; ++s) {
    int h = 1 << s;
    int j = lane & (h - 1);
    float ang = 3.14159265358979f * (float)j / (float)h;
    float ts_, tc_;
    __sincosf(ang, &ts_, &tc_);
    bool up = (lane >> s) & 1;
    tw.g[s]   = up ? -1.f : 1.f;
    tw.dwr[s] = up ? tc_ : 1.f;
    tw.dwi[s] = up ? -ts_ : 0.f;
  }
  __sincosf(3.14159265358979f * (float)lane * (1.f / 64.f), &tw.ts6, &tw.tc6);

  // ---- P0: load probe rows + forward row FFT (ILP-4) --------------------
  const v2f* probe2 = (const v2f*)probe;
#pragma unroll 1
  for (int k0 = 0; k0 < 8; k0 += 4) {
    int r0 = wid * 8 + k0;
    v2f A[4], B[4];
#pragma unroll
    for (int kk = 0; kk < 4; ++kk) {
      A[kk] = probe2[(p * NP + r0 + kk) * NP + lane];
      B[kk] = probe2[(p * NP + r0 + kk) * NP + lane + 64];
    }
#pragma unroll
    for (int kk = 0; kk < 4; ++kk) dif128(A[kk], B[kk], tw, bp32);
#pragma unroll
    for (int kk = 0; kk < 4; ++kk) {
      fld[(r0 + kk) * LSTR + lane]      = A[kk];
      fld[(r0 + kk) * LSTR + lane + 64] = B[kk];
    }
  }
  __syncthreads();

  // fallback-only multiplies (no workspace)
  auto ramp_mul_fb = [&](v2f& A, v2f& B, int c) {
    float sh0v = shifts[2 * pos], sh1v = shifts[2 * pos + 1];
    int kxc = br7(c);
    float fx = (float)(kxc < 64 ? kxc : kxc - 128) * (1.f / 128.f);
    int ky0 = br7(lane);
    float fy0 = (float)(ky0 < 64 ? ky0 : ky0 - 128) * (1.f / 128.f);
    int ky1 = ky0 + 1;
    float fy1 = (float)(ky1 < 64 ? ky1 : ky1 - 128) * (1.f / 128.f);
    float com = fx * sh1v;
    float s0, c0_, s1, c1_;
    __sincosf(-6.28318530717959f * (fy0 * sh0v + com), &s0, &c0_);
    __sincosf(-6.28318530717959f * (fy1 * sh0v + com), &s1, &c1_);
    A = cmulv(A, c0_ * INV_N2, s0 * INV_N2);
    B = cmulv(B, c1_ * INV_N2, s1 * INV_N2);
  };
  auto h_mul_fb = [&](v2f& A, v2f& B, int c) {
    int kx = br7(c), ky0 = br7(lane);
    float hr0 = H[(ky0 * NP + kx) * 2], hi0 = H[(ky0 * NP + kx) * 2 + 1];
    float hr1 = H[((ky0 + 1) * NP + kx) * 2], hi1 = H[((ky0 + 1) * NP + kx) * 2 + 1];
    A = cmulv(A, hr0 * INV_N2, hi0 * INV_N2);
    B = cmulv(B, hr1 * INV_N2, hi1 * INV_N2);
  };

  // ---- column phase: Fcol, freq multiply, invCol (ILP-4) ----------------
  auto cphase = [&](int mode) {
    v2f ry0, ry1;
    if (mode == 0 && mode_ws) {
      float2 t0 = rampy[n * NP + lane];
      float2 t1 = rampy[n * NP + lane + 64];
      ry0 = (v2f){t0.x, t0.y}; ry1 = (v2f){t1.x, t1.y};
    }
#pragma unroll 1
    for (int k0 = 0; k0 < 8; k0 += 4) {
      int c0 = wid * 8 + k0;
      float2 h0[4], h1[4], rx[4];
      if (mode == 1 && mode_ws) {
#pragma unroll
        for (int kk = 0; kk < 4; ++kk) {
          h0[kk] = hpre[(c0 + kk) * NP + lane];
          h1[kk] = hpre[(c0 + kk) * NP + lane + 64];
        }
      }
      if (mode == 0 && mode_ws) {
#pragma unroll
        for (int kk = 0; kk < 4; ++kk) rx[kk] = rampx[n * NP + c0 + kk];
      }
      v2f A[4], B[4];
#pragma unroll
      for (int kk = 0; kk < 4; ++kk) {
        A[kk] = fld[lane * LSTR + c0 + kk];
        B[kk] = fld[(lane + 64) * LSTR + c0 + kk];
      }
#pragma unroll
      for (int kk = 0; kk < 4; ++kk) dif128(A[kk], B[kk], tw, bp32);
      if (mode == 0) {
        if (mode_ws) {
#pragma unroll
          for (int kk = 0; kk < 4; ++kk) {
            v2f m;
            m = cmulv(ry0, rx[kk].x, rx[kk].y); A[kk] = cmulvv(A[kk], m);
            m = cmulv(ry1, rx[kk].x, rx[kk].y); B[kk] = cmulvv(B[kk], m);
          }
        } else {
#pragma unroll
          for (int kk = 0; kk < 4; ++kk) ramp_mul_fb(A[kk], B[kk], c0 + kk);
        }
      } else {
        if (mode_ws) {
#pragma unroll
          for (int kk = 0; kk < 4; ++kk) {
            A[kk] = cmulv(A[kk], h0[kk].x, h0[kk].y);
            B[kk] = cmulv(B[kk], h1[kk].x, h1[kk].y);
          }
        } else {
#pragma unroll
          for (int kk = 0; kk < 4; ++kk) h_mul_fb(A[kk], B[kk], c0 + kk);
        }
      }
#pragma unroll
      for (int kk = 0; kk < 4; ++kk) dit128(A[kk], B[kk], tw, bp32);
#pragma unroll
      for (int kk = 0; kk < 4; ++kk) {
        fld[lane * LSTR + c0 + kk]        = A[kk];
        fld[(lane + 64) * LSTR + c0 + kk] = B[kk];
      }
    }
    __syncthreads();
  };

  // ---- row phase: invRow, multiply T(z), Frow (ILP-4) -------------------
  auto rphase = [&](int z) {
#pragma unroll 1
    for (int k0 = 0; k0 < 8; k0 += 4) {
      int r0 = wid * 8 + k0;
      size_t ob = ((size_t)(o * NZ + z) * NYX + (size_t)(cy + r0)) * NYX + cx;
      v2f A[4], B[4];
#pragma unroll
      for (int kk = 0; kk < 4; ++kk) {
        A[kk] = fld[(r0 + kk) * LSTR + lane];
        B[kk] = fld[(r0 + kk) * LSTR + lane + 64];
      }
      if (mode_T) {
        float2 t0[4], t1[4];
#pragma unroll
        for (int kk = 0; kk < 4; ++kk) {
          t0[kk] = Tpre[ob + (size_t)kk * NYX + lane];
          t1[kk] = Tpre[ob + (size_t)kk * NYX + lane + 64];
        }
#pragma unroll
        for (int kk = 0; kk < 4; ++kk) dit128(A[kk], B[kk], tw, bp32);
#pragma unroll
        for (int kk = 0; kk < 4; ++kk) {
          A[kk] = cmulv(A[kk], t0[kk].x, t0[kk].y);
          B[kk] = cmulv(B[kk], t1[kk].x, t1[kk].y);
        }
      } else {
        float pa0[4], ph0[4], pa1[4], ph1[4];
#pragma unroll
        for (int kk = 0; kk < 4; ++kk) {
          pa0[kk] = obja[ob + (size_t)kk * NYX + lane];
          ph0[kk] = objp[ob + (size_t)kk * NYX + lane];
          pa1[kk] = obja[ob + (size_t)kk * NYX + lane + 64];
          ph1[kk] = objp[ob + (size_t)kk * NYX + lane + 64];
        }
#pragma unroll
        for (int kk = 0; kk < 4; ++kk) dit128(A[kk], B[kk], tw, bp32);
#pragma unroll
        for (int kk = 0; kk < 4; ++kk) {
          float s, c;
          __sincosf(ph0[kk], &s, &c); A[kk] = cmulv(A[kk], pa0[kk] * c, pa0[kk] * s);
          __sincosf(ph1[kk], &s, &c); B[kk] = cmulv(B[kk], pa1[kk] * c, pa1[kk] * s);
        }
      }
#pragma unroll
      for (int kk = 0; kk < 4; ++kk) dif128(A[kk], B[kk], tw, bp32);
#pragma unroll
      for (int kk = 0; kk < 4; ++kk) {
        fld[(r0 + kk) * LSTR + lane]      = A[kk];
        fld[(r0 + kk) * LSTR + lane + 64] = B[kk];
      }
    }
    __syncthreads();
  };

  cphase(0);        // Fcol + ramp + invCol  (completes probe shift)
  rphase(0);        // invRow + T0 + Frow
#pragma unroll 1
  for (int z = 1; z < NZ; ++z) {
    cphase(1);      // Fcol + H + invCol     (propagation z-1 -> z)
    rphase(z);      // invRow + Tz + Frow
  }

  // ---- final column FFT -> |.|^2 -> store (transposed part tile) --------
#pragma unroll 1
  for (int k0 = 0; k0 < 8; k0 += 4) {
    int c0 = wid * 8 + k0;
    v2f A[4], B[4];
#pragma unroll
    for (int kk = 0; kk < 4; ++kk) {
      A[kk] = fld[lane * LSTR + c0 + kk];
      B[kk] = fld[(lane + 64) * LSTR + c0 + kk];
    }
#pragma unroll
    for (int kk = 0; kk < 4; ++kk) dif128(A[kk], B[kk], tw, bp32);
    int ky0 = br7(lane);
#pragma unroll
    for (int kk = 0; kk < 4; ++kk) {
      float m0 = fmaf(A[kk].x, A[kk].x, A[kk].y * A[kk].y);
      float m1 = fmaf(B[kk].x, B[kk].x, B[kk].y * B[kk].y);
      if (mode_ws) {
        size_t b0 = ((size_t)blk << 14) + (size_t)br7(c0 + kk) * NP;
        part[b0 + ky0]     = m0;    // occupancy weight applied in reduce_dp
        part[b0 + ky0 + 1] = m1;
      } else {
        size_t base = ((size_t)n << 14);
        atomicAdd(&dp[base + (size_t)ky0 * NP + br7(c0 + kk)],       m0 * wocc);
        atomicAdd(&dp[base + (size_t)(ky0 + 1) * NP + br7(c0 + kk)], m1 * wocc);
      }
    }
  }
}

extern "C" void kernel_launch(void* const* d_in, const int* in_sizes, int n_in,
                              void* d_out, int out_size, void* d_ws, size_t ws_size,
                              hipStream_t stream) {
  const float* obja   = (const float*)d_in[0];
  const float* objp   = (const float*)d_in[1];
  const float* probe  = (const float*)d_in[2];
  const float* shifts = (const float*)d_in[3];
  const float* H      = (const float*)d_in[4];
  const float* occu   = (const float*)d_in[5];
  const int*   indices = (const int*)d_in[6];
  const int*   crop    = (const int*)d_in[7];
  float* dp = (float*)d_out;

  const size_t part_bytes  = (size_t)BATCH * OMODE * PMODE * NP * NP * sizeof(float); // 32 MB
  const size_t hpre_bytes  = (size_t)NP * NP * sizeof(float2);                        // 128 KB
  const size_t ramp_bytes  = (size_t)BATCH * NP * sizeof(float2);                     // 64 KB each
  const size_t T_bytes     = (size_t)OMODE * NZ * NYX * NYX * sizeof(float2);         // 33.5 MB
  const size_t need_ws = part_bytes + hpre_bytes + 2 * ramp_bytes;
  const size_t need_T  = need_ws + T_bytes;

  int mode_ws = (ws_size >= need_ws) ? 1 : 0;
  int mode_T  = (ws_size >= need_T) ? 1 : 0;
  float*  part  = (float*)d_ws;
  float2* hpre  = (float2*)((char*)d_ws + part_bytes);
  float2* rampy = (float2*)((char*)d_ws + part_bytes + hpre_bytes);
  float2* rampx = (float2*)((char*)d_ws + part_bytes + hpre_bytes + ramp_bytes);
  float2* Tpre  = (float2*)((char*)d_ws + need_ws);

  if (mode_ws) {
    hipLaunchKernelGGL(init_hpre, dim3((NP * NP + 255) / 256), dim3(256), 0,
                       stream, H, hpre);
    hipLaunchKernelGGL(init_ramp, dim3((2 * BATCH * NP + 255) / 256), dim3(256), 0,
                       stream, shifts, indices, rampy, rampx);
  } else {
    // atomic fallback accumulates -> must zero output every call
    hipMemsetAsync(d_out, 0, (size_t)out_size * sizeof(float), stream);
  }
  if (mode_T) {
    hipLaunchKernelGGL(init_T, dim3((OMODE * NZ * NYX * NYX + 255) / 256), dim3(256),
                       0, stream, obja, objp, Tpre);
  }

  const int lds_bytes = NP * LSTR * (int)sizeof(float2);  // 132096
  hipFuncSetAttribute((const void*)ptycho_chain,
                      hipFuncAttributeMaxDynamicSharedMemorySize, lds_bytes);
  hipLaunchKernelGGL(ptycho_chain, dim3(BATCH * OMODE * PMODE), dim3(1024),
                     lds_bytes, stream,
                     obja, objp, probe, shifts, H, hpre, rampy, rampx, Tpre,
                     occu, indices, crop, dp, part, mode_ws, mode_T);
  if (mode_ws) {
    hipLaunchKernelGGL(reduce_dp, dim3((BATCH * NP * NP + 255) / 256), dim3(256),
                       0, stream, part, occu, dp);
  }
}